// Round 1
// baseline (1656.397 us; speedup 1.0000x reference)
//
#include <hip/hip_runtime.h>
#include <hip/hip_bf16.h>

#define Hdim 128
#define Kn 48
#define Btot 2
#define Ldim 2048
#define NN (Btot * Ldim) /* 4096 nodes */
#define FFH 512
#define LN_EPS 1e-5f

__device__ __forceinline__ float gelu_f(float x) {
    return 0.5f * x * (1.0f + erff(x * 0.7071067811865475f));
}

// ---------------------------------------------------------------------------
// pre: selfA[n][o] = b[o] + sum_i hV[n][i]*W[i][o]   (W rows 0..127)
//      nbC [n][o] =        sum_i hV[n][i]*W[256+i][o] (W rows 256..383)
// 8 nodes per block, 128 threads.
// ---------------------------------------------------------------------------
__global__ __launch_bounds__(128) void pre_kernel(
    const float* __restrict__ hV, const float* __restrict__ W,
    const float* __restrict__ b, float* __restrict__ selfA,
    float* __restrict__ nbC) {
    __shared__ __align__(16) float xs[8][Hdim];
    const int o = threadIdx.x;
    const int n0 = blockIdx.x * 8;
    for (int n = 0; n < 8; ++n) xs[n][o] = hV[(size_t)(n0 + n) * Hdim + o];
    __syncthreads();
    float accA[8], accC[8];
    const float bo = b[o];
#pragma unroll
    for (int n = 0; n < 8; ++n) { accA[n] = bo; accC[n] = 0.0f; }
    for (int i = 0; i < Hdim; i += 4) {
        const float wA0 = W[(i + 0) * Hdim + o];
        const float wA1 = W[(i + 1) * Hdim + o];
        const float wA2 = W[(i + 2) * Hdim + o];
        const float wA3 = W[(i + 3) * Hdim + o];
        const float wC0 = W[(256 + i + 0) * Hdim + o];
        const float wC1 = W[(256 + i + 1) * Hdim + o];
        const float wC2 = W[(256 + i + 2) * Hdim + o];
        const float wC3 = W[(256 + i + 3) * Hdim + o];
#pragma unroll
        for (int n = 0; n < 8; ++n) {
            const float4 v = *(const float4*)&xs[n][i];
            accA[n] = fmaf(v.x, wA0, accA[n]);
            accA[n] = fmaf(v.y, wA1, accA[n]);
            accA[n] = fmaf(v.z, wA2, accA[n]);
            accA[n] = fmaf(v.w, wA3, accA[n]);
            accC[n] = fmaf(v.x, wC0, accC[n]);
            accC[n] = fmaf(v.y, wC1, accC[n]);
            accC[n] = fmaf(v.z, wC2, accC[n]);
            accC[n] = fmaf(v.w, wC3, accC[n]);
        }
    }
#pragma unroll
    for (int n = 0; n < 8; ++n) {
        selfA[(size_t)(n0 + n) * Hdim + o] = accA[n];
        nbC[(size_t)(n0 + n) * Hdim + o] = accC[n];
    }
}

// ---------------------------------------------------------------------------
// node_msg: one block per node. 48 edges in registers (acc over k).
//   layer1_in[k] = selfA[n] + hE[k] @ W1b + nbC[idx_k]
//   msg = (gelu(gelu(layer1_in) @ W2 + b2)) @ W3 + b3
//   dh = sum_k mask_att[k]*msg[k] / 30 ; hV2 = LN1(hV + dh)
// ---------------------------------------------------------------------------
__global__ __launch_bounds__(128) void node_msg_kernel(
    const float* __restrict__ hV, const float* __restrict__ hE,
    const int* __restrict__ Eidx, const float* __restrict__ maskAtt,
    const float* __restrict__ selfA, const float* __restrict__ nbC,
    const float* __restrict__ W1m, const float* __restrict__ W2,
    const float* __restrict__ b2, const float* __restrict__ W3,
    const float* __restrict__ b3, const float* __restrict__ g1,
    const float* __restrict__ be1, float* __restrict__ hV2) {
    __shared__ __align__(16) float buf[Kn][Hdim];  // 24 KB
    __shared__ int idx_s[Kn];
    __shared__ float ma_s[Kn];
    __shared__ float rw[4];
    const int o = threadIdx.x;
    const int n = blockIdx.x;
    const size_t ebase = (size_t)n * Kn * Hdim;
    // stage h_E rows (flat coalesced copy)
    float* bufflat = &buf[0][0];
    for (int t = o; t < Kn * Hdim; t += 128) bufflat[t] = hE[ebase + t];
    if (o < Kn) {
        idx_s[o] = Eidx[(size_t)n * Kn + o];
        ma_s[o] = maskAtt[(size_t)n * Kn + o];
    }
    __syncthreads();

    const int bbase = (n >> 11) << 11;  // b*L
    float accs[Kn];
    // init with gathered neighbor contribution
#pragma unroll
    for (int k = 0; k < Kn; ++k)
        accs[k] = nbC[(size_t)(bbase + idx_s[k]) * Hdim + o];
    const float sA = selfA[(size_t)n * Hdim + o];

    // layer 1 (edge part)
    for (int i = 0; i < Hdim; i += 4) {
        const float w0 = W1m[(i + 0) * Hdim + o];
        const float w1 = W1m[(i + 1) * Hdim + o];
        const float w2 = W1m[(i + 2) * Hdim + o];
        const float w3 = W1m[(i + 3) * Hdim + o];
#pragma unroll
        for (int k = 0; k < Kn; ++k) {
            const float4 v = *(const float4*)&buf[k][i];
            accs[k] = fmaf(v.x, w0, accs[k]);
            accs[k] = fmaf(v.y, w1, accs[k]);
            accs[k] = fmaf(v.z, w2, accs[k]);
            accs[k] = fmaf(v.w, w3, accs[k]);
        }
    }
#pragma unroll
    for (int k = 0; k < Kn; ++k) accs[k] = gelu_f(accs[k] + sA);
    __syncthreads();
#pragma unroll
    for (int k = 0; k < Kn; ++k) buf[k][o] = accs[k];
    __syncthreads();

    // layer 2
    const float b2o = b2[o];
#pragma unroll
    for (int k = 0; k < Kn; ++k) accs[k] = b2o;
    for (int i = 0; i < Hdim; i += 4) {
        const float w0 = W2[(i + 0) * Hdim + o];
        const float w1 = W2[(i + 1) * Hdim + o];
        const float w2 = W2[(i + 2) * Hdim + o];
        const float w3 = W2[(i + 3) * Hdim + o];
#pragma unroll
        for (int k = 0; k < Kn; ++k) {
            const float4 v = *(const float4*)&buf[k][i];
            accs[k] = fmaf(v.x, w0, accs[k]);
            accs[k] = fmaf(v.y, w1, accs[k]);
            accs[k] = fmaf(v.z, w2, accs[k]);
            accs[k] = fmaf(v.w, w3, accs[k]);
        }
    }
#pragma unroll
    for (int k = 0; k < Kn; ++k) accs[k] = gelu_f(accs[k]);
    __syncthreads();
#pragma unroll
    for (int k = 0; k < Kn; ++k) buf[k][o] = accs[k];
    __syncthreads();

    // layer 3 (no activation)
    const float b3o = b3[o];
#pragma unroll
    for (int k = 0; k < Kn; ++k) accs[k] = b3o;
    for (int i = 0; i < Hdim; i += 4) {
        const float w0 = W3[(i + 0) * Hdim + o];
        const float w1 = W3[(i + 1) * Hdim + o];
        const float w2 = W3[(i + 2) * Hdim + o];
        const float w3 = W3[(i + 3) * Hdim + o];
#pragma unroll
        for (int k = 0; k < Kn; ++k) {
            const float4 v = *(const float4*)&buf[k][i];
            accs[k] = fmaf(v.x, w0, accs[k]);
            accs[k] = fmaf(v.y, w1, accs[k]);
            accs[k] = fmaf(v.z, w2, accs[k]);
            accs[k] = fmaf(v.w, w3, accs[k]);
        }
    }

    // masked sum over k, /30
    float dh = 0.0f;
#pragma unroll
    for (int k = 0; k < Kn; ++k) dh = fmaf(ma_s[k], accs[k], dh);
    dh *= (1.0f / 30.0f);

    // LN1 over the 128 channels of this block
    const float x = hV[(size_t)n * Hdim + o] + dh;
    float s = x, s2 = x * x;
#pragma unroll
    for (int off = 32; off > 0; off >>= 1) {
        s += __shfl_xor(s, off);
        s2 += __shfl_xor(s2, off);
    }
    if ((o & 63) == 0) {
        rw[(o >> 6) * 2] = s;
        rw[(o >> 6) * 2 + 1] = s2;
    }
    __syncthreads();
    const float ts = rw[0] + rw[2], ts2 = rw[1] + rw[3];
    const float mu = ts * (1.0f / Hdim);
    const float var = ts2 * (1.0f / Hdim) - mu * mu;
    const float rs = rsqrtf(var + LN_EPS);
    hV2[(size_t)n * Hdim + o] = g1[o] * (x - mu) * rs + be1[o];
}

// ---------------------------------------------------------------------------
// ffn: 8 nodes/block.  hV3 = mask_V * LN2(hV2 + gelu(hV2@W_in+b_in)@W_out+b_out)
// ---------------------------------------------------------------------------
__global__ __launch_bounds__(128) void ffn_kernel(
    const float* __restrict__ hV2, const float* __restrict__ W_in,
    const float* __restrict__ b_in, const float* __restrict__ W_out,
    const float* __restrict__ b_out, const float* __restrict__ g2,
    const float* __restrict__ be2, const float* __restrict__ maskV,
    float* __restrict__ hV3) {
    __shared__ __align__(16) float xs[8][Hdim];   // 4 KB
    __shared__ __align__(16) float hs[8][FFH];    // 16 KB
    __shared__ float rw[4];
    const int o = threadIdx.x;
    const int n0 = blockIdx.x * 8;
    for (int n = 0; n < 8; ++n) xs[n][o] = hV2[(size_t)(n0 + n) * Hdim + o];
    __syncthreads();

    for (int jg = 0; jg < 4; ++jg) {
        const int j = jg * Hdim + o;
        float acc[8];
        const float bj = b_in[j];
#pragma unroll
        for (int n = 0; n < 8; ++n) acc[n] = bj;
        for (int i = 0; i < Hdim; i += 4) {
            const float w0 = W_in[(i + 0) * FFH + j];
            const float w1 = W_in[(i + 1) * FFH + j];
            const float w2 = W_in[(i + 2) * FFH + j];
            const float w3 = W_in[(i + 3) * FFH + j];
#pragma unroll
            for (int n = 0; n < 8; ++n) {
                const float4 v = *(const float4*)&xs[n][i];
                acc[n] = fmaf(v.x, w0, acc[n]);
                acc[n] = fmaf(v.y, w1, acc[n]);
                acc[n] = fmaf(v.z, w2, acc[n]);
                acc[n] = fmaf(v.w, w3, acc[n]);
            }
        }
#pragma unroll
        for (int n = 0; n < 8; ++n) hs[n][j] = gelu_f(acc[n]);
    }
    __syncthreads();

    float acc2[8];
    const float bo = b_out[o];
#pragma unroll
    for (int n = 0; n < 8; ++n) acc2[n] = bo;
    for (int j = 0; j < FFH; j += 4) {
        const float w0 = W_out[(j + 0) * Hdim + o];
        const float w1 = W_out[(j + 1) * Hdim + o];
        const float w2 = W_out[(j + 2) * Hdim + o];
        const float w3 = W_out[(j + 3) * Hdim + o];
#pragma unroll
        for (int n = 0; n < 8; ++n) {
            const float4 v = *(const float4*)&hs[n][j];
            acc2[n] = fmaf(v.x, w0, acc2[n]);
            acc2[n] = fmaf(v.y, w1, acc2[n]);
            acc2[n] = fmaf(v.z, w2, acc2[n]);
            acc2[n] = fmaf(v.w, w3, acc2[n]);
        }
    }

    for (int n = 0; n < 8; ++n) {
        const float x = xs[n][o] + acc2[n];
        float s = x, s2 = x * x;
#pragma unroll
        for (int off = 32; off > 0; off >>= 1) {
            s += __shfl_xor(s, off);
            s2 += __shfl_xor(s2, off);
        }
        if ((o & 63) == 0) {
            rw[(o >> 6) * 2] = s;
            rw[(o >> 6) * 2 + 1] = s2;
        }
        __syncthreads();
        const float ts = rw[0] + rw[2], ts2 = rw[1] + rw[3];
        __syncthreads();
        const float mu = ts * (1.0f / Hdim);
        const float var = ts2 * (1.0f / Hdim) - mu * mu;
        const float rs = rsqrtf(var + LN_EPS);
        const float y = (g2[o] * (x - mu) * rs + be2[o]) * maskV[n0 + n];
        hV3[(size_t)(n0 + n) * Hdim + o] = y;
    }
}

// ---------------------------------------------------------------------------
// edge_upd: one block per node. msg through W11/W12/W13, then per-edge LN3
//   hE_out[k] = LN3(hE[k] + msg[k])
// ---------------------------------------------------------------------------
__global__ __launch_bounds__(128) void edge_upd_kernel(
    const float* __restrict__ hV3, const float* __restrict__ hE,
    const int* __restrict__ Eidx, const float* __restrict__ selfA,
    const float* __restrict__ nbC, const float* __restrict__ W11m,
    const float* __restrict__ W12, const float* __restrict__ b12,
    const float* __restrict__ W13, const float* __restrict__ b13,
    const float* __restrict__ g3, const float* __restrict__ be3,
    float* __restrict__ hEout) {
    __shared__ __align__(16) float res[Kn][Hdim];  // original h_E, 24 KB
    __shared__ __align__(16) float buf[Kn][Hdim];  // work, 24 KB
    __shared__ int idx_s[Kn];
    __shared__ float mu_s[Kn], rs_s[Kn];
    const int o = threadIdx.x;
    const int n = blockIdx.x;
    const size_t ebase = (size_t)n * Kn * Hdim;
    float* resflat = &res[0][0];
    for (int t = o; t < Kn * Hdim; t += 128) resflat[t] = hE[ebase + t];
    if (o < Kn) idx_s[o] = Eidx[(size_t)n * Kn + o];
    __syncthreads();

    const int bbase = (n >> 11) << 11;
    float accs[Kn];
#pragma unroll
    for (int k = 0; k < Kn; ++k)
        accs[k] = nbC[(size_t)(bbase + idx_s[k]) * Hdim + o];
    const float sA = selfA[(size_t)n * Hdim + o];

    // layer 1 (reads res)
    for (int i = 0; i < Hdim; i += 4) {
        const float w0 = W11m[(i + 0) * Hdim + o];
        const float w1 = W11m[(i + 1) * Hdim + o];
        const float w2 = W11m[(i + 2) * Hdim + o];
        const float w3 = W11m[(i + 3) * Hdim + o];
#pragma unroll
        for (int k = 0; k < Kn; ++k) {
            const float4 v = *(const float4*)&res[k][i];
            accs[k] = fmaf(v.x, w0, accs[k]);
            accs[k] = fmaf(v.y, w1, accs[k]);
            accs[k] = fmaf(v.z, w2, accs[k]);
            accs[k] = fmaf(v.w, w3, accs[k]);
        }
    }
#pragma unroll
    for (int k = 0; k < Kn; ++k) buf[k][o] = gelu_f(accs[k] + sA);
    __syncthreads();

    // layer 2
    const float b2o = b12[o];
#pragma unroll
    for (int k = 0; k < Kn; ++k) accs[k] = b2o;
    for (int i = 0; i < Hdim; i += 4) {
        const float w0 = W12[(i + 0) * Hdim + o];
        const float w1 = W12[(i + 1) * Hdim + o];
        const float w2 = W12[(i + 2) * Hdim + o];
        const float w3 = W12[(i + 3) * Hdim + o];
#pragma unroll
        for (int k = 0; k < Kn; ++k) {
            const float4 v = *(const float4*)&buf[k][i];
            accs[k] = fmaf(v.x, w0, accs[k]);
            accs[k] = fmaf(v.y, w1, accs[k]);
            accs[k] = fmaf(v.z, w2, accs[k]);
            accs[k] = fmaf(v.w, w3, accs[k]);
        }
    }
    __syncthreads();
#pragma unroll
    for (int k = 0; k < Kn; ++k) buf[k][o] = gelu_f(accs[k]);
    __syncthreads();

    // layer 3
    const float b3o = b13[o];
#pragma unroll
    for (int k = 0; k < Kn; ++k) accs[k] = b3o;
    for (int i = 0; i < Hdim; i += 4) {
        const float w0 = W13[(i + 0) * Hdim + o];
        const float w1 = W13[(i + 1) * Hdim + o];
        const float w2 = W13[(i + 2) * Hdim + o];
        const float w3 = W13[(i + 3) * Hdim + o];
#pragma unroll
        for (int k = 0; k < Kn; ++k) {
            const float4 v = *(const float4*)&buf[k][i];
            accs[k] = fmaf(v.x, w0, accs[k]);
            accs[k] = fmaf(v.y, w1, accs[k]);
            accs[k] = fmaf(v.z, w2, accs[k]);
            accs[k] = fmaf(v.w, w3, accs[k]);
        }
    }
    __syncthreads();

    // x = residual + msg, stage into buf for per-row LN
#pragma unroll
    for (int k = 0; k < Kn; ++k) buf[k][o] = res[k][o] + accs[k];
    __syncthreads();

    if (o < Kn) {
        float s = 0.0f, s2 = 0.0f;
        for (int ii = 0; ii < Hdim; ++ii) {
            const float v = buf[o][(ii + o) & (Hdim - 1)];  // stagger: no bank conflict
            s += v;
            s2 += v * v;
        }
        const float mu = s * (1.0f / Hdim);
        const float var = s2 * (1.0f / Hdim) - mu * mu;
        mu_s[o] = mu;
        rs_s[o] = rsqrtf(var + LN_EPS);
    }
    __syncthreads();

    const float go = g3[o], beo = be3[o];
#pragma unroll
    for (int k = 0; k < Kn; ++k) {
        const float y = go * (buf[k][o] - mu_s[k]) * rs_s[k] + beo;
        hEout[ebase + (size_t)k * Hdim + o] = y;
    }
}

// ---------------------------------------------------------------------------
extern "C" void kernel_launch(void* const* d_in, const int* in_sizes, int n_in,
                              void* d_out, int out_size, void* d_ws,
                              size_t ws_size, hipStream_t stream) {
    const float* hV = (const float*)d_in[0];
    const float* hE = (const float*)d_in[1];
    const int* Eidx = (const int*)d_in[2];
    const float* maskV = (const float*)d_in[3];
    const float* maskAtt = (const float*)d_in[4];
    const float* W1 = (const float*)d_in[5];
    const float* b1 = (const float*)d_in[6];
    const float* W2 = (const float*)d_in[7];
    const float* b2 = (const float*)d_in[8];
    const float* W3 = (const float*)d_in[9];
    const float* b3 = (const float*)d_in[10];
    const float* W11 = (const float*)d_in[11];
    const float* b11 = (const float*)d_in[12];
    const float* W12 = (const float*)d_in[13];
    const float* b12 = (const float*)d_in[14];
    const float* W13 = (const float*)d_in[15];
    const float* b13 = (const float*)d_in[16];
    const float* g1 = (const float*)d_in[17];
    const float* be1 = (const float*)d_in[18];
    const float* g2 = (const float*)d_in[19];
    const float* be2 = (const float*)d_in[20];
    const float* g3 = (const float*)d_in[21];
    const float* be3 = (const float*)d_in[22];
    const float* W_in = (const float*)d_in[23];
    const float* b_in = (const float*)d_in[24];
    const float* W_out = (const float*)d_in[25];
    const float* b_out = (const float*)d_in[26];

    float* out_hV = (float*)d_out;                       // 4096*128
    float* out_hE = out_hV + (size_t)NN * Hdim;          // 4096*48*128
    float* ws = (float*)d_ws;
    float* hV2 = ws;                                     // 524288 floats
    float* selfA = ws + (size_t)NN * Hdim;               // 524288 floats
    float* nbC = ws + 2 * (size_t)NN * Hdim;             // 524288 floats

    // phase 1: node message + LN1
    pre_kernel<<<NN / 8, 128, 0, stream>>>(hV, W1, b1, selfA, nbC);
    node_msg_kernel<<<NN, 128, 0, stream>>>(hV, hE, Eidx, maskAtt, selfA, nbC,
                                            W1 + 128 * Hdim, W2, b2, W3, b3,
                                            g1, be1, hV2);
    // phase 2: FFN + LN2 + mask_V  -> h_V output
    ffn_kernel<<<NN / 8, 128, 0, stream>>>(hV2, W_in, b_in, W_out, b_out, g2,
                                           be2, maskV, out_hV);
    // phase 3: edge update + LN3 -> h_E output
    pre_kernel<<<NN / 8, 128, 0, stream>>>(out_hV, W11, b11, selfA, nbC);
    edge_upd_kernel<<<NN, 128, 0, stream>>>(out_hV, hE, Eidx, selfA, nbC,
                                            W11 + 128 * Hdim, W12, b12, W13,
                                            b13, g3, be3, out_hE);
}

// Round 2
// 651.928 us; speedup vs baseline: 2.5408x; 2.5408x over previous
//
#include <hip/hip_runtime.h>
#include <hip/hip_bf16.h>
#include <math.h>

#define Hdim 128
#define Kn 48
#define NN 4096
#define FFH 512
#define LN_EPS 1e-5f

typedef __attribute__((ext_vector_type(8))) short bf16x8;
typedef __attribute__((ext_vector_type(4))) float floatx4;

__device__ __forceinline__ float gelu_f(float x) {
    return 0.5f * x * (1.0f + erff(x * 0.7071067811865475f));
}

__device__ __forceinline__ unsigned short f2bf(float f) {
    union { float f; unsigned u; } v;
    v.f = f;
    unsigned r = v.u + 0x7FFF + ((v.u >> 16) & 1);
    return (unsigned short)(r >> 16);
}

// ---------------------------------------------------------------------------
// convert_wT: dst[n*K + k] = bf16( src[(rowOff+k)*N + n] )   (transpose+cast)
// ---------------------------------------------------------------------------
__global__ void convert_wT(const float* __restrict__ src,
                           unsigned short* __restrict__ dst, int logK, int N,
                           int rowOff, int total) {
    int d = blockIdx.x * 256 + threadIdx.x;
    if (d >= total) return;
    int k = d & ((1 << logK) - 1);
    int n = d >> logK;
    dst[d] = f2bf(src[(size_t)(rowOff + k) * N + n]);
}

// ---------------------------------------------------------------------------
// pre: selfA[n][o] = b[o] + sum_i hV[n][i]*W[i][o]   (W rows 0..127)
//      nbC [n][o] =        sum_i hV[n][i]*W[256+i][o] (W rows 256..383)
// ---------------------------------------------------------------------------
__global__ __launch_bounds__(128) void pre_kernel(
    const float* __restrict__ hV, const float* __restrict__ W,
    const float* __restrict__ b, float* __restrict__ selfA,
    float* __restrict__ nbC) {
    __shared__ __align__(16) float xs[8][Hdim];
    const int o = threadIdx.x;
    const int n0 = blockIdx.x * 8;
    for (int n = 0; n < 8; ++n) xs[n][o] = hV[(size_t)(n0 + n) * Hdim + o];
    __syncthreads();
    float accA[8], accC[8];
    const float bo = b[o];
#pragma unroll
    for (int n = 0; n < 8; ++n) { accA[n] = bo; accC[n] = 0.0f; }
    for (int i = 0; i < Hdim; i += 4) {
        const float wA0 = W[(i + 0) * Hdim + o];
        const float wA1 = W[(i + 1) * Hdim + o];
        const float wA2 = W[(i + 2) * Hdim + o];
        const float wA3 = W[(i + 3) * Hdim + o];
        const float wC0 = W[(256 + i + 0) * Hdim + o];
        const float wC1 = W[(256 + i + 1) * Hdim + o];
        const float wC2 = W[(256 + i + 2) * Hdim + o];
        const float wC3 = W[(256 + i + 3) * Hdim + o];
#pragma unroll
        for (int n = 0; n < 8; ++n) {
            const float4 v = *(const float4*)&xs[n][i];
            accA[n] = fmaf(v.x, wA0, accA[n]);
            accA[n] = fmaf(v.y, wA1, accA[n]);
            accA[n] = fmaf(v.z, wA2, accA[n]);
            accA[n] = fmaf(v.w, wA3, accA[n]);
            accC[n] = fmaf(v.x, wC0, accC[n]);
            accC[n] = fmaf(v.y, wC1, accC[n]);
            accC[n] = fmaf(v.z, wC2, accC[n]);
            accC[n] = fmaf(v.w, wC3, accC[n]);
        }
    }
#pragma unroll
    for (int n = 0; n < 8; ++n) {
        selfA[(size_t)(n0 + n) * Hdim + o] = accA[n];
        nbC[(size_t)(n0 + n) * Hdim + o] = accC[n];
    }
}

// ---------------------------------------------------------------------------
// Shared helpers for the MFMA kernels
// ---------------------------------------------------------------------------
__device__ __forceinline__ void stage_w(char* WBuf, const unsigned short* Wt,
                                        int tid, int nthr) {
    const uint4* src = (const uint4*)Wt;
    for (int i = tid; i < 2048; i += nthr) {
        uint4 v = src[i];
        int n = i >> 4, c = i & 15;
        *(uint4*)(WBuf + ((n * 256 + c * 16) ^ ((n & 7) << 4))) = v;
    }
}

__device__ __forceinline__ void gemm_layer(const char* X, const char* W,
                                           floatx4 acc[3][4], int wm, int wn,
                                           int l15, int l4) {
#pragma unroll
    for (int kk = 0; kk < 4; ++kk) {
        bf16x8 a[3], b[4];
#pragma unroll
        for (int mt = 0; mt < 3; ++mt) {
            int row = wm * 48 + mt * 16 + l15;
            a[mt] = *(const bf16x8*)(X + (row * 256 +
                     ((kk * 64 + l4 * 16) ^ ((row & 7) << 4))));
        }
#pragma unroll
        for (int nt = 0; nt < 4; ++nt) {
            int row = wn * 64 + nt * 16 + l15;
            b[nt] = *(const bf16x8*)(W + (row * 256 +
                     ((kk * 64 + l4 * 16) ^ ((row & 7) << 4))));
        }
#pragma unroll
        for (int mt = 0; mt < 3; ++mt)
#pragma unroll
            for (int nt = 0; nt < 4; ++nt)
                acc[mt][nt] = __builtin_amdgcn_mfma_f32_16x16x32_bf16(
                    a[mt], b[nt], acc[mt][nt], 0, 0, 0);
    }
}

// ---------------------------------------------------------------------------
// edge_mlp<MODE>: 4 nodes/block, 512 threads, 8 waves (4 M-groups x 2 N-halves)
// 3-layer MLP over the node's 48 edges via 16x16x32 bf16 MFMA.
// MODE 0 (node message): masked col-sum /30, +hV, LN1 -> hV2 (fp32 ws)
// MODE 1 (edge update):  +hE residual, per-row LN3 -> out_hE
// ---------------------------------------------------------------------------
template <int MODE>
__global__ __launch_bounds__(512) void edge_mlp(
    const float* __restrict__ hV, const float* __restrict__ hE,
    const int* __restrict__ Eidx, const float* __restrict__ maskAtt,
    const float* __restrict__ selfA, const float* __restrict__ nbC,
    const unsigned short* __restrict__ WtA,
    const unsigned short* __restrict__ WtB,
    const unsigned short* __restrict__ WtC, const float* __restrict__ bias2,
    const float* __restrict__ bias3, const float* __restrict__ gamma,
    const float* __restrict__ beta, float* __restrict__ outp) {
    __shared__ __align__(16) char WB[32768];
    __shared__ __align__(16) char B0[49152];
    __shared__ __align__(16) char B1[49152];
    __shared__ float dh_s[4][128];
    __shared__ float rsum[192][2];
    __shared__ float rsum2[192][2];
    __shared__ float mu_s[192], rs_s[192];
    __shared__ float rw[16];

    const int tid = threadIdx.x;
    const int lane = tid & 63;
    const int wid = tid >> 6;
    const int wm = wid >> 1;  // which node of the 4 (M-group)
    const int wn = wid & 1;   // which 64-col half
    const int l15 = lane & 15;
    const int l4 = lane >> 4;

    // ---- stage edge features hE -> B0 (fp32 -> bf16, swizzled) ----
    {
        const float4* src = (const float4*)(hE + (size_t)blockIdx.x * 24576);
#pragma unroll
        for (int it = 0; it < 12; ++it) {
            int i = tid + it * 512;
            float4 v = src[i];
            int f = i * 4;
            int m = f >> 7, c = f & 127;
            unsigned lo = f2bf(v.x) | ((unsigned)f2bf(v.y) << 16);
            unsigned hi = f2bf(v.z) | ((unsigned)f2bf(v.w) << 16);
            *(uint2*)(B0 + ((m * 256 + c * 2) ^ ((m & 7) << 4))) =
                make_uint2(lo, hi);
        }
    }
    stage_w(WB, WtA, tid, 512);
    __syncthreads();

    floatx4 acc[3][4];
#pragma unroll
    for (int mt = 0; mt < 3; ++mt)
#pragma unroll
        for (int nt = 0; nt < 4; ++nt) acc[mt][nt] = (floatx4)0.0f;
    gemm_layer(B0, WB, acc, wm, wn, l15, l4);

    // ---- layer-1 epilogue: + selfA + gathered nbC, GELU -> B1 ----
    const int gnode = blockIdx.x * 4 + wm;
    const int bbase = (gnode >> 11) << 11;
    int nbr[3][4];
#pragma unroll
    for (int mt = 0; mt < 3; ++mt)
#pragma unroll
        for (int r = 0; r < 4; ++r)
            nbr[mt][r] = Eidx[(size_t)gnode * Kn + mt * 16 + l4 * 4 + r];
    float sA[4];
#pragma unroll
    for (int nt = 0; nt < 4; ++nt)
        sA[nt] = selfA[(size_t)gnode * Hdim + wn * 64 + nt * 16 + l15];
#pragma unroll
    for (int mt = 0; mt < 3; ++mt)
#pragma unroll
        for (int nt = 0; nt < 4; ++nt) {
            const int ncol = wn * 64 + nt * 16 + l15;
#pragma unroll
            for (int r = 0; r < 4; ++r) {
                float v = acc[mt][nt][r] + sA[nt] +
                          nbC[(size_t)(bbase + nbr[mt][r]) * Hdim + ncol];
                v = gelu_f(v);
                int row = wm * 48 + mt * 16 + l4 * 4 + r;
                *(unsigned short*)(B1 + ((row * 256 + ncol * 2) ^
                                         ((row & 7) << 4))) = f2bf(v);
            }
        }
    __syncthreads();

    // ---- layer 2 ----
    stage_w(WB, WtB, tid, 512);
    __syncthreads();
    {
        float bv[4];
#pragma unroll
        for (int nt = 0; nt < 4; ++nt)
            bv[nt] = bias2[wn * 64 + nt * 16 + l15];
#pragma unroll
        for (int mt = 0; mt < 3; ++mt)
#pragma unroll
            for (int nt = 0; nt < 4; ++nt)
                acc[mt][nt] = (floatx4){bv[nt], bv[nt], bv[nt], bv[nt]};
    }
    gemm_layer(B1, WB, acc, wm, wn, l15, l4);
#pragma unroll
    for (int mt = 0; mt < 3; ++mt)
#pragma unroll
        for (int nt = 0; nt < 4; ++nt) {
            const int ncol = wn * 64 + nt * 16 + l15;
#pragma unroll
            for (int r = 0; r < 4; ++r) {
                float v = gelu_f(acc[mt][nt][r]);
                int row = wm * 48 + mt * 16 + l4 * 4 + r;
                *(unsigned short*)(B0 + ((row * 256 + ncol * 2) ^
                                         ((row & 7) << 4))) = f2bf(v);
            }
        }
    __syncthreads();

    // ---- layer 3 ----
    stage_w(WB, WtC, tid, 512);
    __syncthreads();
    {
        float bv[4];
#pragma unroll
        for (int nt = 0; nt < 4; ++nt)
            bv[nt] = bias3[wn * 64 + nt * 16 + l15];
#pragma unroll
        for (int mt = 0; mt < 3; ++mt)
#pragma unroll
            for (int nt = 0; nt < 4; ++nt)
                acc[mt][nt] = (floatx4){bv[nt], bv[nt], bv[nt], bv[nt]};
    }
    gemm_layer(B0, WB, acc, wm, wn, l15, l4);

    if (MODE == 0) {
        // masked column-sum over the node's 48 edges, /30, +hV, LN1
        float mav[3][4];
#pragma unroll
        for (int mt = 0; mt < 3; ++mt)
#pragma unroll
            for (int r = 0; r < 4; ++r)
                mav[mt][r] =
                    maskAtt[(size_t)gnode * Kn + mt * 16 + l4 * 4 + r];
#pragma unroll
        for (int nt = 0; nt < 4; ++nt) {
            float c = 0.0f;
#pragma unroll
            for (int mt = 0; mt < 3; ++mt)
#pragma unroll
                for (int r = 0; r < 4; ++r)
                    c = fmaf(mav[mt][r], acc[mt][nt][r], c);
            c += __shfl_xor(c, 16);
            c += __shfl_xor(c, 32);
            if (l4 == 0) dh_s[wm][wn * 64 + nt * 16 + l15] = c;
        }
        __syncthreads();
        const int nl = tid >> 7, ch = tid & 127;
        const size_t gn2 = (size_t)(blockIdx.x * 4 + nl);
        float x = hV[gn2 * Hdim + ch] + dh_s[nl][ch] * (1.0f / 30.0f);
        float s = x, s2 = x * x;
#pragma unroll
        for (int off = 32; off > 0; off >>= 1) {
            s += __shfl_xor(s, off);
            s2 += __shfl_xor(s2, off);
        }
        if (lane == 0) {
            rw[wid * 2] = s;
            rw[wid * 2 + 1] = s2;
        }
        __syncthreads();
        const float ts = rw[4 * nl] + rw[4 * nl + 2];
        const float ts2 = rw[4 * nl + 1] + rw[4 * nl + 3];
        const float mu = ts * (1.0f / Hdim);
        const float var = ts2 * (1.0f / Hdim) - mu * mu;
        const float rs = rsqrtf(var + LN_EPS);
        outp[gn2 * Hdim + ch] = gamma[ch] * (x - mu) * rs + beta[ch];
    } else {
        // residual + per-edge-row LN3 -> h_E out
        const size_t erow0 = (size_t)blockIdx.x * 192 + wm * 48;
#pragma unroll
        for (int mt = 0; mt < 3; ++mt)
#pragma unroll
            for (int nt = 0; nt < 4; ++nt) {
                const int ncol = wn * 64 + nt * 16 + l15;
#pragma unroll
                for (int r = 0; r < 4; ++r)
                    acc[mt][nt][r] +=
                        hE[(erow0 + mt * 16 + l4 * 4 + r) * Hdim + ncol];
            }
#pragma unroll
        for (int mt = 0; mt < 3; ++mt)
#pragma unroll
            for (int r = 0; r < 4; ++r) {
                float s = 0.0f, s2 = 0.0f;
#pragma unroll
                for (int nt = 0; nt < 4; ++nt) {
                    float t = acc[mt][nt][r];
                    s += t;
                    s2 += t * t;
                }
#pragma unroll
                for (int off = 1; off < 16; off <<= 1) {
                    s += __shfl_xor(s, off);
                    s2 += __shfl_xor(s2, off);
                }
                if (l15 == 0) {
                    int row = wm * 48 + mt * 16 + l4 * 4 + r;
                    rsum[row][wn] = s;
                    rsum2[row][wn] = s2;
                }
            }
        __syncthreads();
        if (tid < 192) {
            float s = rsum[tid][0] + rsum[tid][1];
            float s2 = rsum2[tid][0] + rsum2[tid][1];
            float mu = s * (1.0f / Hdim);
            float var = s2 * (1.0f / Hdim) - mu * mu;
            mu_s[tid] = mu;
            rs_s[tid] = rsqrtf(var + LN_EPS);
        }
        __syncthreads();
        float gv[4], bv[4];
#pragma unroll
        for (int nt = 0; nt < 4; ++nt) {
            gv[nt] = gamma[wn * 64 + nt * 16 + l15];
            bv[nt] = beta[wn * 64 + nt * 16 + l15];
        }
#pragma unroll
        for (int mt = 0; mt < 3; ++mt)
#pragma unroll
            for (int nt = 0; nt < 4; ++nt) {
                const int ncol = wn * 64 + nt * 16 + l15;
#pragma unroll
                for (int r = 0; r < 4; ++r) {
                    int row = wm * 48 + mt * 16 + l4 * 4 + r;
                    float y = gv[nt] * (acc[mt][nt][r] - mu_s[row]) *
                                  rs_s[row] + bv[nt];
                    outp[(erow0 + mt * 16 + l4 * 4 + r) * Hdim + ncol] = y;
                }
            }
    }
}

// ---------------------------------------------------------------------------
// ffn_mfma: 16 nodes/block, 256 threads. H=gelu(X@W_in+b_in); y=H@W_out+b_out
// then residual + LN2 + mask_V -> out_hV. Weights streamed in 32KB chunks.
// ---------------------------------------------------------------------------
__global__ __launch_bounds__(256) void ffn_mfma(
    const float* __restrict__ hV2, const unsigned short* __restrict__ WtIn,
    const float* __restrict__ b_in, const unsigned short* __restrict__ WtOut,
    const float* __restrict__ b_out, const float* __restrict__ g2,
    const float* __restrict__ be2, const float* __restrict__ maskV,
    float* __restrict__ outp) {
    __shared__ __align__(16) char XF[4096];
    __shared__ __align__(16) char HF[16384];
    __shared__ __align__(16) char WF[32768];
    __shared__ float rsF[16][4], rs2F[16][4], muF[16], rstdF[16];

    const int tid = threadIdx.x;
    const int lane = tid & 63;
    const int wid = tid >> 6;
    const int l15 = lane & 15, l4 = lane >> 4;
    const int rg0 = blockIdx.x * 16;

    {
        const float4* src = (const float4*)(hV2 + (size_t)rg0 * Hdim);
#pragma unroll
        for (int it = 0; it < 2; ++it) {
            int i = tid + it * 256;
            float4 v = src[i];
            int f = i * 4;
            int m = f >> 7, c = f & 127;
            unsigned lo = f2bf(v.x) | ((unsigned)f2bf(v.y) << 16);
            unsigned hi = f2bf(v.z) | ((unsigned)f2bf(v.w) << 16);
            *(uint2*)(XF + ((m * 256 + c * 2) ^ ((m & 7) << 4))) =
                make_uint2(lo, hi);
        }
    }
    // L1 over 4 column chunks of 128
    for (int c = 0; c < 4; ++c) {
        {
            const uint4* src = (const uint4*)(WtIn + (size_t)c * 16384);
#pragma unroll
            for (int it = 0; it < 8; ++it) {
                int i = tid + it * 256;
                uint4 v = src[i];
                int n = i >> 4, k16 = i & 15;
                *(uint4*)(WF + ((n * 256 + k16 * 16) ^ ((n & 7) << 4))) = v;
            }
        }
        __syncthreads();
        floatx4 a2[2];
#pragma unroll
        for (int nt = 0; nt < 2; ++nt) {
            float bv = b_in[c * 128 + wid * 32 + nt * 16 + l15];
            a2[nt] = (floatx4){bv, bv, bv, bv};
        }
#pragma unroll
        for (int kk = 0; kk < 4; ++kk) {
            int row = l15;
            bf16x8 af = *(const bf16x8*)(XF + (row * 256 +
                         ((kk * 64 + l4 * 16) ^ ((row & 7) << 4))));
#pragma unroll
            for (int nt = 0; nt < 2; ++nt) {
                int wr = wid * 32 + nt * 16 + l15;
                bf16x8 bf = *(const bf16x8*)(WF + (wr * 256 +
                             ((kk * 64 + l4 * 16) ^ ((wr & 7) << 4))));
                a2[nt] = __builtin_amdgcn_mfma_f32_16x16x32_bf16(af, bf,
                                                                 a2[nt], 0, 0, 0);
            }
        }
#pragma unroll
        for (int nt = 0; nt < 2; ++nt) {
            const int col = c * 128 + wid * 32 + nt * 16 + l15;
#pragma unroll
            for (int r = 0; r < 4; ++r) {
                int m = l4 * 4 + r;
                float v = gelu_f(a2[nt][r]);
                *(unsigned short*)(HF + ((m * 1024 + col * 2) ^
                                         ((m & 7) << 4))) = f2bf(v);
            }
        }
        __syncthreads();
    }
    // L2 over 4 K chunks of 128
    floatx4 o2[2];
#pragma unroll
    for (int nt = 0; nt < 2; ++nt) {
        float bv = b_out[wid * 32 + nt * 16 + l15];
        o2[nt] = (floatx4){bv, bv, bv, bv};
    }
    for (int kc = 0; kc < 4; ++kc) {
        {
#pragma unroll
            for (int it = 0; it < 8; ++it) {
                int i = tid + it * 256;
                int n = i >> 4, k16 = i & 15;
                uint4 v = *(const uint4*)(WtOut + (size_t)n * FFH + kc * 128 +
                                          k16 * 8);
                *(uint4*)(WF + ((n * 256 + k16 * 16) ^ ((n & 7) << 4))) = v;
            }
        }
        __syncthreads();
#pragma unroll
        for (int kk = 0; kk < 4; ++kk) {
            int row = l15;
            bf16x8 af = *(const bf16x8*)(HF + (row * 1024 +
                         ((kc * 256 + kk * 64 + l4 * 16) ^ ((row & 7) << 4))));
#pragma unroll
            for (int nt = 0; nt < 2; ++nt) {
                int wr = wid * 32 + nt * 16 + l15;
                bf16x8 bf = *(const bf16x8*)(WF + (wr * 256 +
                             ((kk * 64 + l4 * 16) ^ ((wr & 7) << 4))));
                o2[nt] = __builtin_amdgcn_mfma_f32_16x16x32_bf16(af, bf,
                                                                 o2[nt], 0, 0, 0);
            }
        }
        __syncthreads();
    }
    // epilogue: residual + LN2 + mask
    float xv[2][4];
#pragma unroll
    for (int nt = 0; nt < 2; ++nt) {
        const int ncol = wid * 32 + nt * 16 + l15;
#pragma unroll
        for (int r = 0; r < 4; ++r) {
            int m = l4 * 4 + r;
            xv[nt][r] = hV2[(size_t)(rg0 + m) * Hdim + ncol] + o2[nt][r];
        }
    }
#pragma unroll
    for (int r = 0; r < 4; ++r) {
        float s = xv[0][r] + xv[1][r];
        float s2 = xv[0][r] * xv[0][r] + xv[1][r] * xv[1][r];
#pragma unroll
        for (int off = 1; off < 16; off <<= 1) {
            s += __shfl_xor(s, off);
            s2 += __shfl_xor(s2, off);
        }
        if (l15 == 0) {
            int m = l4 * 4 + r;
            rsF[m][wid] = s;
            rs2F[m][wid] = s2;
        }
    }
    __syncthreads();
    if (tid < 16) {
        float s = rsF[tid][0] + rsF[tid][1] + rsF[tid][2] + rsF[tid][3];
        float s2 = rs2F[tid][0] + rs2F[tid][1] + rs2F[tid][2] + rs2F[tid][3];
        float mu = s * (1.0f / Hdim);
        float var = s2 * (1.0f / Hdim) - mu * mu;
        muF[tid] = mu;
        rstdF[tid] = rsqrtf(var + LN_EPS);
    }
    __syncthreads();
#pragma unroll
    for (int nt = 0; nt < 2; ++nt) {
        const int ncol = wid * 32 + nt * 16 + l15;
        float gvv = g2[ncol], bvv = be2[ncol];
#pragma unroll
        for (int r = 0; r < 4; ++r) {
            int m = l4 * 4 + r;
            float y = (gvv * (xv[nt][r] - muF[m]) * rstdF[m] + bvv) *
                      maskV[rg0 + m];
            outp[(size_t)(rg0 + m) * Hdim + ncol] = y;
        }
    }
}

// ---------------------------------------------------------------------------
extern "C" void kernel_launch(void* const* d_in, const int* in_sizes, int n_in,
                              void* d_out, int out_size, void* d_ws,
                              size_t ws_size, hipStream_t stream) {
    const float* hV = (const float*)d_in[0];
    const float* hE = (const float*)d_in[1];
    const int* Eidx = (const int*)d_in[2];
    const float* maskV = (const float*)d_in[3];
    const float* maskAtt = (const float*)d_in[4];
    const float* W1 = (const float*)d_in[5];
    const float* b1 = (const float*)d_in[6];
    const float* W2 = (const float*)d_in[7];
    const float* b2 = (const float*)d_in[8];
    const float* W3 = (const float*)d_in[9];
    const float* b3 = (const float*)d_in[10];
    const float* W11 = (const float*)d_in[11];
    const float* b11 = (const float*)d_in[12];
    const float* W12 = (const float*)d_in[13];
    const float* b12 = (const float*)d_in[14];
    const float* W13 = (const float*)d_in[15];
    const float* b13 = (const float*)d_in[16];
    const float* g1 = (const float*)d_in[17];
    const float* be1 = (const float*)d_in[18];
    const float* g2 = (const float*)d_in[19];
    const float* be2 = (const float*)d_in[20];
    const float* g3 = (const float*)d_in[21];
    const float* be3 = (const float*)d_in[22];
    const float* W_in = (const float*)d_in[23];
    const float* b_in = (const float*)d_in[24];
    const float* W_out = (const float*)d_in[25];
    const float* b_out = (const float*)d_in[26];

    float* out_hV = (float*)d_out;
    float* out_hE = out_hV + (size_t)NN * Hdim;
    float* ws = (float*)d_ws;
    float* hV2 = ws;                          // 524288 f32
    float* selfA = ws + 524288;               // 524288 f32
    float* nbC = ws + 1048576;                // 524288 f32
    unsigned short* wbf = (unsigned short*)(ws + 1572864);
    unsigned short* Wt1b = wbf;               // 16384 each
    unsigned short* Wt2 = wbf + 16384;
    unsigned short* Wt3 = wbf + 32768;
    unsigned short* Wt11b = wbf + 49152;
    unsigned short* Wt12 = wbf + 65536;
    unsigned short* Wt13 = wbf + 81920;
    unsigned short* WtIn = wbf + 98304;       // 65536
    unsigned short* WtOut = wbf + 163840;     // 65536

    // weight transposes/casts (bf16)
    convert_wT<<<64, 256, 0, stream>>>(W1, Wt1b, 7, 128, 128, 16384);
    convert_wT<<<64, 256, 0, stream>>>(W2, Wt2, 7, 128, 0, 16384);
    convert_wT<<<64, 256, 0, stream>>>(W3, Wt3, 7, 128, 0, 16384);
    convert_wT<<<64, 256, 0, stream>>>(W11, Wt11b, 7, 128, 128, 16384);
    convert_wT<<<64, 256, 0, stream>>>(W12, Wt12, 7, 128, 0, 16384);
    convert_wT<<<64, 256, 0, stream>>>(W13, Wt13, 7, 128, 0, 16384);
    convert_wT<<<256, 256, 0, stream>>>(W_in, WtIn, 7, 512, 0, 65536);
    convert_wT<<<256, 256, 0, stream>>>(W_out, WtOut, 9, 128, 0, 65536);

    // phase 1: node message + LN1 -> hV2
    pre_kernel<<<NN / 8, 128, 0, stream>>>(hV, W1, b1, selfA, nbC);
    edge_mlp<0><<<NN / 4, 512, 0, stream>>>(hV, hE, Eidx, maskAtt, selfA, nbC,
                                            Wt1b, Wt2, Wt3, b2, b3, g1, be1,
                                            hV2);
    // phase 2: FFN + LN2 + mask -> out_hV
    ffn_mfma<<<NN / 16, 256, 0, stream>>>(hV2, WtIn, b_in, WtOut, b_out, g2,
                                          be2, maskV, out_hV);
    // phase 3: edge update + LN3 -> out_hE
    pre_kernel<<<NN / 8, 128, 0, stream>>>(out_hV, W11, b11, selfA, nbC);
    edge_mlp<1><<<NN / 4, 512, 0, stream>>>(nullptr, hE, Eidx, nullptr, selfA,
                                            nbC, Wt11b, Wt12, Wt13, b12, b13,
                                            g3, be3, out_hE);
}

// Round 3
// 411.530 us; speedup vs baseline: 4.0250x; 1.5842x over previous
//
#include <hip/hip_runtime.h>
#include <hip/hip_bf16.h>
#include <math.h>

#define Hdim 128
#define Kn 48
#define NN 4096
#define FFH 512
#define LN_EPS 1e-5f

typedef __attribute__((ext_vector_type(8))) short bf16x8;
typedef __attribute__((ext_vector_type(4))) float floatx4;
typedef unsigned short ushort_t;

// tanh-approx GELU: gelu(x) = x * sigmoid(2*0.7978845608*(x+0.044715x^3))
// = x * 1/(1+exp2(-x*(2.3022081 + 0.1029454*x^2))).  |err vs erf-gelu| <~3e-3.
__device__ __forceinline__ float gelu_f(float x) {
    float x2 = x * x;
    float u = x * fmaf(x2, -0.1029454f, -2.3022081f);
    return x * __builtin_amdgcn_rcpf(1.0f + exp2f(u));
}

__device__ __forceinline__ ushort_t f2bf(float f) {
    union { float f; unsigned u; } v;
    v.f = f;
    unsigned r = v.u + 0x7FFF + ((v.u >> 16) & 1);
    return (ushort_t)(r >> 16);
}
__device__ __forceinline__ float bf2f(ushort_t h) {
    union { unsigned u; float f; } v;
    v.u = ((unsigned)h) << 16;
    return v.f;
}

// ---------------------------------------------------------------------------
// convert_all: all weight transposes (fp32 -> bf16, [N][K] row-major) + hV bf16
// ---------------------------------------------------------------------------
__global__ __launch_bounds__(256) void convert_all(
    const float* __restrict__ W1, const float* __restrict__ W11,
    const float* __restrict__ W2, const float* __restrict__ W3,
    const float* __restrict__ W12, const float* __restrict__ W13,
    const float* __restrict__ W_in, const float* __restrict__ W_out,
    const float* __restrict__ hV, ushort_t* __restrict__ Wt1m,
    ushort_t* __restrict__ Wt11m, ushort_t* __restrict__ Wt2,
    ushort_t* __restrict__ Wt3, ushort_t* __restrict__ Wt12,
    ushort_t* __restrict__ Wt13, ushort_t* __restrict__ WtIn,
    ushort_t* __restrict__ WtOut, ushort_t* __restrict__ hVbf) {
    const int b = blockIdx.x, t = threadIdx.x;
    if (b < 128) {        // Wt1m[n*256+k] = W1[(128+k)*128+n]
        int s = b * 256 + t, k = s >> 7, n = s & 127;
        Wt1m[n * 256 + k] = f2bf(W1[16384 + s]);
    } else if (b < 256) {
        int s = (b - 128) * 256 + t, k = s >> 7, n = s & 127;
        Wt11m[n * 256 + k] = f2bf(W11[16384 + s]);
    } else if (b < 320) {
        int s = (b - 256) * 256 + t, k = s >> 7, n = s & 127;
        Wt2[n * 128 + k] = f2bf(W2[s]);
    } else if (b < 384) {
        int s = (b - 320) * 256 + t, k = s >> 7, n = s & 127;
        Wt3[n * 128 + k] = f2bf(W3[s]);
    } else if (b < 448) {
        int s = (b - 384) * 256 + t, k = s >> 7, n = s & 127;
        Wt12[n * 128 + k] = f2bf(W12[s]);
    } else if (b < 512) {
        int s = (b - 448) * 256 + t, k = s >> 7, n = s & 127;
        Wt13[n * 128 + k] = f2bf(W13[s]);
    } else if (b < 768) {  // WtIn[n*128+k] = W_in[k*512+n]
        int s = (b - 512) * 256 + t, k = s >> 9, n = s & 511;
        WtIn[n * 128 + k] = f2bf(W_in[s]);
    } else if (b < 1024) { // WtOut[n*512+k] = W_out[k*128+n]
        int s = (b - 768) * 256 + t, k = s >> 7, n = s & 127;
        WtOut[n * 512 + k] = f2bf(W_out[s]);
    } else {               // hV -> bf16, 8 elems/thread
        int i = (b - 1024) * 256 + t;
        float4 a = *(const float4*)(hV + (size_t)i * 8);
        float4 c = *(const float4*)(hV + (size_t)i * 8 + 4);
        ushort_t o[8] = {f2bf(a.x), f2bf(a.y), f2bf(a.z), f2bf(a.w),
                         f2bf(c.x), f2bf(c.y), f2bf(c.z), f2bf(c.w)};
        *(uint4*)(hVbf + (size_t)i * 8) = *(const uint4*)o;
    }
}

// ---------------------------------------------------------------------------
// pre_self: selfA[n][o] = b[o] + sum_i hV[n][i]*W[i][o]  (W rows 0..127)
// ---------------------------------------------------------------------------
__global__ __launch_bounds__(128) void pre_self(const float* __restrict__ hV,
                                                const float* __restrict__ W,
                                                const float* __restrict__ b,
                                                float* __restrict__ selfA) {
    __shared__ __align__(16) float xs[8][Hdim];
    const int o = threadIdx.x;
    const int n0 = blockIdx.x * 8;
    for (int n = 0; n < 8; ++n) xs[n][o] = hV[(size_t)(n0 + n) * Hdim + o];
    __syncthreads();
    float acc[8];
    const float bo = b[o];
#pragma unroll
    for (int n = 0; n < 8; ++n) acc[n] = bo;
    for (int i = 0; i < Hdim; i += 4) {
        const float w0 = W[(i + 0) * Hdim + o];
        const float w1 = W[(i + 1) * Hdim + o];
        const float w2 = W[(i + 2) * Hdim + o];
        const float w3 = W[(i + 3) * Hdim + o];
#pragma unroll
        for (int n = 0; n < 8; ++n) {
            const float4 v = *(const float4*)&xs[n][i];
            acc[n] = fmaf(v.x, w0, acc[n]);
            acc[n] = fmaf(v.y, w1, acc[n]);
            acc[n] = fmaf(v.z, w2, acc[n]);
            acc[n] = fmaf(v.w, w3, acc[n]);
        }
    }
#pragma unroll
    for (int n = 0; n < 8; ++n) selfA[(size_t)(n0 + n) * Hdim + o] = acc[n];
}

// ---------------------------------------------------------------------------
// edge_mlp<MODE>: 1 node/block, 256 threads (4 waves, each wave owns 32 cols).
// Layer-1 input tile in LDS: [hE(128) | gathered hV_nbr(128)] bf16, K=256.
// Weights read directly from global (L2-hot). Self part added from selfA.
// MODE 0: masked col-sum /30, +hV, LN1 -> hV2 (fp32 ws)
// MODE 1: +hE residual (bf16 from LDS), per-row LN3 -> out_hE
// ---------------------------------------------------------------------------
template <int MODE>
__global__ __launch_bounds__(256, 3) void edge_mlp(
    const float* __restrict__ hV, const float* __restrict__ hE,
    const int* __restrict__ Eidx, const float* __restrict__ maskAtt,
    const float* __restrict__ selfA, const ushort_t* __restrict__ hVbf,
    const ushort_t* __restrict__ WtA, const ushort_t* __restrict__ WtB,
    const ushort_t* __restrict__ WtC, const float* __restrict__ bias2,
    const float* __restrict__ bias3, const float* __restrict__ gamma,
    const float* __restrict__ beta, float* __restrict__ outp) {
    __shared__ __align__(16) char T0[24576];  // 48 x 256 bf16, stride 512B
    __shared__ __align__(16) char T1[12288];  // 48 x 128 bf16, stride 256B
    __shared__ __align__(16) char T2[12288];
    __shared__ int idx_s[Kn];
    __shared__ float dh_s[128];
    __shared__ float rsum[Kn][4], rsum2[Kn][4];
    __shared__ float mu_s[Kn], rs_s[Kn];
    __shared__ float rw[8];

    const int tid = threadIdx.x;
    const int lane = tid & 63;
    const int w = tid >> 6;
    const int l15 = lane & 15, l4 = lane >> 4;
    const int n = blockIdx.x;
    const int n0 = w * 32;
    const int bbase = (n >> 11) << 11;

    if (tid < Kn) idx_s[tid] = Eidx[(size_t)n * Kn + tid];
    // stage hE (fp32 -> bf16, swizzled)
    {
        const float4* src = (const float4*)(hE + (size_t)n * Kn * Hdim);
#pragma unroll
        for (int it = 0; it < 6; ++it) {
            int i = tid + it * 256;
            float4 v = src[i];
            int row = i >> 5, c = i & 31;
            unsigned lo = f2bf(v.x) | ((unsigned)f2bf(v.y) << 16);
            unsigned hi = f2bf(v.z) | ((unsigned)f2bf(v.w) << 16);
            *(uint2*)(T0 + row * 512 + ((c * 8) ^ ((row & 7) << 4))) =
                make_uint2(lo, hi);
        }
    }
    __syncthreads();
    // gather neighbor bf16 rows into T0 cols 128..255 (coalesced 16B chunks)
#pragma unroll
    for (int it = 0; it < 3; ++it) {
        int i = tid + it * 256;
        int row = i >> 4, c = i & 15;
        uint4 v =
            *(const uint4*)(hVbf + (size_t)(bbase + idx_s[row]) * Hdim + c * 8);
        *(uint4*)(T0 + row * 512 + ((256 + c * 16) ^ ((row & 7) << 4))) = v;
    }
    __syncthreads();

    floatx4 acc[3][2];
#pragma unroll
    for (int mt = 0; mt < 3; ++mt)
#pragma unroll
        for (int nt = 0; nt < 2; ++nt) acc[mt][nt] = (floatx4)0.0f;

    // ---- layer 1: K=256 ----
#pragma unroll
    for (int kk = 0; kk < 8; ++kk) {
        bf16x8 a[3], bb[2];
#pragma unroll
        for (int mt = 0; mt < 3; ++mt) {
            int row = mt * 16 + l15;
            a[mt] = *(const bf16x8*)(T0 + row * 512 +
                     ((kk * 64 + l4 * 16) ^ ((row & 7) << 4)));
        }
#pragma unroll
        for (int nt = 0; nt < 2; ++nt)
            bb[nt] = *(const bf16x8*)(WtA + (n0 + nt * 16 + l15) * 256 +
                                      kk * 32 + l4 * 8);
#pragma unroll
        for (int mt = 0; mt < 3; ++mt)
#pragma unroll
            for (int nt = 0; nt < 2; ++nt)
                acc[mt][nt] = __builtin_amdgcn_mfma_f32_16x16x32_bf16(
                    a[mt], bb[nt], acc[mt][nt], 0, 0, 0);
    }
    // layer-1 epilogue: + selfA (broadcast), GELU -> T1
    {
        float sA[2];
#pragma unroll
        for (int nt = 0; nt < 2; ++nt)
            sA[nt] = selfA[(size_t)n * Hdim + n0 + nt * 16 + l15];
#pragma unroll
        for (int mt = 0; mt < 3; ++mt)
#pragma unroll
            for (int nt = 0; nt < 2; ++nt) {
                const int col = n0 + nt * 16 + l15;
#pragma unroll
                for (int r = 0; r < 4; ++r) {
                    float v = gelu_f(acc[mt][nt][r] + sA[nt]);
                    int row = mt * 16 + l4 * 4 + r;
                    *(ushort_t*)(T1 + row * 256 +
                                 ((col * 2) ^ ((row & 7) << 4))) = f2bf(v);
                }
            }
    }
    __syncthreads();

    // ---- layer 2: K=128 ----
    {
        float bv[2];
#pragma unroll
        for (int nt = 0; nt < 2; ++nt) bv[nt] = bias2[n0 + nt * 16 + l15];
#pragma unroll
        for (int mt = 0; mt < 3; ++mt)
#pragma unroll
            for (int nt = 0; nt < 2; ++nt)
                acc[mt][nt] = (floatx4){bv[nt], bv[nt], bv[nt], bv[nt]};
    }
#pragma unroll
    for (int kk = 0; kk < 4; ++kk) {
        bf16x8 a[3], bb[2];
#pragma unroll
        for (int mt = 0; mt < 3; ++mt) {
            int row = mt * 16 + l15;
            a[mt] = *(const bf16x8*)(T1 + row * 256 +
                     ((kk * 64 + l4 * 16) ^ ((row & 7) << 4)));
        }
#pragma unroll
        for (int nt = 0; nt < 2; ++nt)
            bb[nt] = *(const bf16x8*)(WtB + (n0 + nt * 16 + l15) * 128 +
                                      kk * 32 + l4 * 8);
#pragma unroll
        for (int mt = 0; mt < 3; ++mt)
#pragma unroll
            for (int nt = 0; nt < 2; ++nt)
                acc[mt][nt] = __builtin_amdgcn_mfma_f32_16x16x32_bf16(
                    a[mt], bb[nt], acc[mt][nt], 0, 0, 0);
    }
#pragma unroll
    for (int mt = 0; mt < 3; ++mt)
#pragma unroll
        for (int nt = 0; nt < 2; ++nt) {
            const int col = n0 + nt * 16 + l15;
#pragma unroll
            for (int r = 0; r < 4; ++r) {
                float v = gelu_f(acc[mt][nt][r]);
                int row = mt * 16 + l4 * 4 + r;
                *(ushort_t*)(T2 + row * 256 + ((col * 2) ^ ((row & 7) << 4))) =
                    f2bf(v);
            }
        }
    __syncthreads();

    // ---- layer 3: K=128, no activation ----
    {
        float bv[2];
#pragma unroll
        for (int nt = 0; nt < 2; ++nt) bv[nt] = bias3[n0 + nt * 16 + l15];
#pragma unroll
        for (int mt = 0; mt < 3; ++mt)
#pragma unroll
            for (int nt = 0; nt < 2; ++nt)
                acc[mt][nt] = (floatx4){bv[nt], bv[nt], bv[nt], bv[nt]};
    }
#pragma unroll
    for (int kk = 0; kk < 4; ++kk) {
        bf16x8 a[3], bb[2];
#pragma unroll
        for (int mt = 0; mt < 3; ++mt) {
            int row = mt * 16 + l15;
            a[mt] = *(const bf16x8*)(T2 + row * 256 +
                     ((kk * 64 + l4 * 16) ^ ((row & 7) << 4)));
        }
#pragma unroll
        for (int nt = 0; nt < 2; ++nt)
            bb[nt] = *(const bf16x8*)(WtC + (n0 + nt * 16 + l15) * 128 +
                                      kk * 32 + l4 * 8);
#pragma unroll
        for (int mt = 0; mt < 3; ++mt)
#pragma unroll
            for (int nt = 0; nt < 2; ++nt)
                acc[mt][nt] = __builtin_amdgcn_mfma_f32_16x16x32_bf16(
                    a[mt], bb[nt], acc[mt][nt], 0, 0, 0);
    }

    if (MODE == 0) {
        // masked column-sum over 48 edges, /30, +hV, LN1
        float mav[3][4];
#pragma unroll
        for (int mt = 0; mt < 3; ++mt)
#pragma unroll
            for (int r = 0; r < 4; ++r)
                mav[mt][r] =
                    maskAtt[(size_t)n * Kn + mt * 16 + l4 * 4 + r];
#pragma unroll
        for (int nt = 0; nt < 2; ++nt) {
            float c = 0.0f;
#pragma unroll
            for (int mt = 0; mt < 3; ++mt)
#pragma unroll
                for (int r = 0; r < 4; ++r)
                    c = fmaf(mav[mt][r], acc[mt][nt][r], c);
            c += __shfl_xor(c, 16);
            c += __shfl_xor(c, 32);
            if (l4 == 0) dh_s[n0 + nt * 16 + l15] = c;
        }
        __syncthreads();
        float x = 0.0f;
        if (tid < 128) {
            x = hV[(size_t)n * Hdim + tid] + dh_s[tid] * (1.0f / 30.0f);
            float s = x, s2 = x * x;
#pragma unroll
            for (int off = 32; off > 0; off >>= 1) {
                s += __shfl_xor(s, off);
                s2 += __shfl_xor(s2, off);
            }
            if (lane == 0) {
                rw[(tid >> 6) * 2] = s;
                rw[(tid >> 6) * 2 + 1] = s2;
            }
        }
        __syncthreads();
        if (tid < 128) {
            const float ts = rw[0] + rw[2], ts2 = rw[1] + rw[3];
            const float mu = ts * (1.0f / Hdim);
            const float var = ts2 * (1.0f / Hdim) - mu * mu;
            const float rs = rsqrtf(var + LN_EPS);
            outp[(size_t)n * Hdim + tid] =
                gamma[tid] * (x - mu) * rs + beta[tid];
        }
    } else {
        // residual (bf16 hE from T0) + per-row LN3 -> out_hE
        float xv[3][2][4];
#pragma unroll
        for (int mt = 0; mt < 3; ++mt)
#pragma unroll
            for (int nt = 0; nt < 2; ++nt) {
                const int col = n0 + nt * 16 + l15;
#pragma unroll
                for (int r = 0; r < 4; ++r) {
                    int row = mt * 16 + l4 * 4 + r;
                    ushort_t hv = *(const ushort_t*)(
                        T0 + row * 512 + ((col * 2) ^ ((row & 7) << 4)));
                    xv[mt][nt][r] = acc[mt][nt][r] + bf2f(hv);
                }
            }
#pragma unroll
        for (int mt = 0; mt < 3; ++mt)
#pragma unroll
            for (int r = 0; r < 4; ++r) {
                float s = xv[mt][0][r] + xv[mt][1][r];
                float s2 = xv[mt][0][r] * xv[mt][0][r] +
                           xv[mt][1][r] * xv[mt][1][r];
#pragma unroll
                for (int off = 1; off < 16; off <<= 1) {
                    s += __shfl_xor(s, off);
                    s2 += __shfl_xor(s2, off);
                }
                if (l15 == 0) {
                    int row = mt * 16 + l4 * 4 + r;
                    rsum[row][w] = s;
                    rsum2[row][w] = s2;
                }
            }
        __syncthreads();
        if (tid < Kn) {
            float s = rsum[tid][0] + rsum[tid][1] + rsum[tid][2] + rsum[tid][3];
            float s2 =
                rsum2[tid][0] + rsum2[tid][1] + rsum2[tid][2] + rsum2[tid][3];
            float mu = s * (1.0f / Hdim);
            float var = s2 * (1.0f / Hdim) - mu * mu;
            mu_s[tid] = mu;
            rs_s[tid] = rsqrtf(var + LN_EPS);
        }
        __syncthreads();
        float gv[2], bv[2];
#pragma unroll
        for (int nt = 0; nt < 2; ++nt) {
            gv[nt] = gamma[n0 + nt * 16 + l15];
            bv[nt] = beta[n0 + nt * 16 + l15];
        }
#pragma unroll
        for (int mt = 0; mt < 3; ++mt)
#pragma unroll
            for (int nt = 0; nt < 2; ++nt) {
                const int col = n0 + nt * 16 + l15;
#pragma unroll
                for (int r = 0; r < 4; ++r) {
                    int row = mt * 16 + l4 * 4 + r;
                    float y = gv[nt] * (xv[mt][nt][r] - mu_s[row]) *
                                  rs_s[row] + bv[nt];
                    outp[((size_t)n * Kn + row) * Hdim + col] = y;
                }
            }
    }
}

// ---------------------------------------------------------------------------
// ffn_mfma: 32 nodes/block, 512 threads (8 waves). Weights direct from global.
// y = LN2(x + gelu(x@W_in+b_in)@W_out+b_out) * maskV -> out fp32 + bf16 copy
// ---------------------------------------------------------------------------
__global__ __launch_bounds__(512) void ffn_mfma(
    const float* __restrict__ hV2, const ushort_t* __restrict__ WtIn,
    const float* __restrict__ b_in, const ushort_t* __restrict__ WtOut,
    const float* __restrict__ b_out, const float* __restrict__ g2,
    const float* __restrict__ be2, const float* __restrict__ maskV,
    float* __restrict__ outp, ushort_t* __restrict__ outb) {
    __shared__ __align__(16) char XF[8192];    // 32 x 128 bf16, stride 256B
    __shared__ __align__(16) char HF[32768];   // 32 x 512 bf16, stride 1024B
    __shared__ float rsF[32][4], rs2F[32][4], muF[32], rstdF[32];

    const int tid = threadIdx.x;
    const int lane = tid & 63;
    const int w = tid >> 6;
    const int wm = w >> 2, wc = w & 3;
    const int l15 = lane & 15, l4 = lane >> 4;
    const int rg0 = blockIdx.x * 32;

    {
        const float4* src = (const float4*)(hV2 + (size_t)rg0 * Hdim);
#pragma unroll
        for (int it = 0; it < 2; ++it) {
            int i = tid + it * 512;
            float4 v = src[i];
            int row = i >> 5, c = i & 31;
            unsigned lo = f2bf(v.x) | ((unsigned)f2bf(v.y) << 16);
            unsigned hi = f2bf(v.z) | ((unsigned)f2bf(v.w) << 16);
            *(uint2*)(XF + row * 256 + ((c * 8) ^ ((row & 7) << 4))) =
                make_uint2(lo, hi);
        }
    }
    __syncthreads();
    // L1: wave (wm, wc): rows wm*16.., cols wc*128..+127 (8 n-tiles)
    {
        floatx4 a1[8];
#pragma unroll
        for (int j = 0; j < 8; ++j) {
            float bv = b_in[wc * 128 + j * 16 + l15];
            a1[j] = (floatx4){bv, bv, bv, bv};
        }
#pragma unroll
        for (int kk = 0; kk < 4; ++kk) {
            int row = wm * 16 + l15;
            bf16x8 af = *(const bf16x8*)(XF + row * 256 +
                         ((kk * 64 + l4 * 16) ^ ((row & 7) << 4)));
#pragma unroll
            for (int j = 0; j < 8; ++j) {
                bf16x8 bf = *(const bf16x8*)(WtIn +
                             (wc * 128 + j * 16 + l15) * 128 + kk * 32 +
                             l4 * 8);
                a1[j] = __builtin_amdgcn_mfma_f32_16x16x32_bf16(af, bf, a1[j],
                                                                0, 0, 0);
            }
        }
#pragma unroll
        for (int j = 0; j < 8; ++j) {
            const int col = wc * 128 + j * 16 + l15;
#pragma unroll
            for (int r = 0; r < 4; ++r) {
                int row = wm * 16 + l4 * 4 + r;
                float v = gelu_f(a1[j][r]);
                *(ushort_t*)(HF + row * 1024 +
                             ((col * 2) ^ ((row & 7) << 4))) = f2bf(v);
            }
        }
    }
    __syncthreads();
    // L2: wave (wm, wc): rows wm*16.., cols (wc*2+{0,1})*16
    floatx4 o2[2];
#pragma unroll
    for (int nt = 0; nt < 2; ++nt) {
        float bv = b_out[(wc * 2 + nt) * 16 + l15];
        o2[nt] = (floatx4){bv, bv, bv, bv};
    }
#pragma unroll
    for (int kk = 0; kk < 16; ++kk) {
        int row = wm * 16 + l15;
        bf16x8 af = *(const bf16x8*)(HF + row * 1024 +
                     ((kk * 64 + l4 * 16) ^ ((row & 7) << 4)));
#pragma unroll
        for (int nt = 0; nt < 2; ++nt) {
            bf16x8 bf = *(const bf16x8*)(WtOut +
                         ((wc * 2 + nt) * 16 + l15) * 512 + kk * 32 + l4 * 8);
            o2[nt] = __builtin_amdgcn_mfma_f32_16x16x32_bf16(af, bf, o2[nt],
                                                             0, 0, 0);
        }
    }
    // epilogue: residual + LN2 + mask -> fp32 out + bf16 copy
    float xv[2][4];
#pragma unroll
    for (int nt = 0; nt < 2; ++nt) {
        const int col = (wc * 2 + nt) * 16 + l15;
#pragma unroll
        for (int r = 0; r < 4; ++r) {
            int row = wm * 16 + l4 * 4 + r;
            xv[nt][r] = hV2[(size_t)(rg0 + row) * Hdim + col] + o2[nt][r];
        }
    }
#pragma unroll
    for (int r = 0; r < 4; ++r) {
        float s = xv[0][r] + xv[1][r];
        float s2 = xv[0][r] * xv[0][r] + xv[1][r] * xv[1][r];
#pragma unroll
        for (int off = 1; off < 16; off <<= 1) {
            s += __shfl_xor(s, off);
            s2 += __shfl_xor(s2, off);
        }
        if (l15 == 0) {
            int row = wm * 16 + l4 * 4 + r;
            rsF[row][wc] = s;
            rs2F[row][wc] = s2;
        }
    }
    __syncthreads();
    if (tid < 32) {
        float s = rsF[tid][0] + rsF[tid][1] + rsF[tid][2] + rsF[tid][3];
        float s2 = rs2F[tid][0] + rs2F[tid][1] + rs2F[tid][2] + rs2F[tid][3];
        float mu = s * (1.0f / Hdim);
        float var = s2 * (1.0f / Hdim) - mu * mu;
        muF[tid] = mu;
        rstdF[tid] = rsqrtf(var + LN_EPS);
    }
    __syncthreads();
#pragma unroll
    for (int nt = 0; nt < 2; ++nt) {
        const int col = (wc * 2 + nt) * 16 + l15;
        float gvv = g2[col], bvv = be2[col];
#pragma unroll
        for (int r = 0; r < 4; ++r) {
            int row = wm * 16 + l4 * 4 + r;
            float y = (gvv * (xv[nt][r] - muF[row]) * rstdF[row] + bvv) *
                      maskV[rg0 + row];
            outp[(size_t)(rg0 + row) * Hdim + col] = y;
            outb[(size_t)(rg0 + row) * Hdim + col] = f2bf(y);
        }
    }
}

// ---------------------------------------------------------------------------
extern "C" void kernel_launch(void* const* d_in, const int* in_sizes, int n_in,
                              void* d_out, int out_size, void* d_ws,
                              size_t ws_size, hipStream_t stream) {
    const float* hV = (const float*)d_in[0];
    const float* hE = (const float*)d_in[1];
    const int* Eidx = (const int*)d_in[2];
    const float* maskV = (const float*)d_in[3];
    const float* maskAtt = (const float*)d_in[4];
    const float* W1 = (const float*)d_in[5];
    const float* b1 = (const float*)d_in[6];
    const float* W2 = (const float*)d_in[7];
    const float* b2 = (const float*)d_in[8];
    const float* W3 = (const float*)d_in[9];
    const float* b3 = (const float*)d_in[10];
    const float* W11 = (const float*)d_in[11];
    const float* b11 = (const float*)d_in[12];
    const float* W12 = (const float*)d_in[13];
    const float* b12 = (const float*)d_in[14];
    const float* W13 = (const float*)d_in[15];
    const float* b13 = (const float*)d_in[16];
    const float* g1 = (const float*)d_in[17];
    const float* be1 = (const float*)d_in[18];
    const float* g2 = (const float*)d_in[19];
    const float* be2 = (const float*)d_in[20];
    const float* g3 = (const float*)d_in[21];
    const float* be3 = (const float*)d_in[22];
    const float* W_in = (const float*)d_in[23];
    const float* b_in = (const float*)d_in[24];
    const float* W_out = (const float*)d_in[25];
    const float* b_out = (const float*)d_in[26];

    float* out_hV = (float*)d_out;
    float* out_hE = out_hV + (size_t)NN * Hdim;
    float* ws = (float*)d_ws;
    float* hV2 = ws;                       // 524288 f32
    float* selfA = ws + 524288;            // 524288 f32
    ushort_t* u = (ushort_t*)(ws + 1048576);
    ushort_t* hVbf = u;                    // 524288
    ushort_t* outVbf = u + 524288;         // 524288
    ushort_t* Wt1m = u + 1048576;          // 32768
    ushort_t* Wt11m = u + 1081344;         // 32768
    ushort_t* Wt2 = u + 1114112;           // 16384
    ushort_t* Wt3 = u + 1130496;           // 16384
    ushort_t* Wt12 = u + 1146880;          // 16384
    ushort_t* Wt13 = u + 1163264;          // 16384
    ushort_t* WtIn = u + 1179648;          // 65536
    ushort_t* WtOut = u + 1245184;         // 65536

    convert_all<<<1280, 256, 0, stream>>>(W1, W11, W2, W3, W12, W13, W_in,
                                          W_out, hV, Wt1m, Wt11m, Wt2, Wt3,
                                          Wt12, Wt13, WtIn, WtOut, hVbf);
    // phase 1: node message + LN1 -> hV2
    pre_self<<<NN / 8, 128, 0, stream>>>(hV, W1, b1, selfA);
    edge_mlp<0><<<NN, 256, 0, stream>>>(hV, hE, Eidx, maskAtt, selfA, hVbf,
                                        Wt1m, Wt2, Wt3, b2, b3, g1, be1, hV2);
    // phase 2: FFN + LN2 + mask -> out_hV (+ bf16 copy)
    ffn_mfma<<<NN / 32, 512, 0, stream>>>(hV2, WtIn, b_in, WtOut, b_out, g2,
                                          be2, maskV, out_hV, outVbf);
    // phase 3: edge update + LN3 -> out_hE
    pre_self<<<NN / 8, 128, 0, stream>>>(out_hV, W11, b11, selfA);
    edge_mlp<1><<<NN, 256, 0, stream>>>(nullptr, hE, Eidx, nullptr, selfA,
                                        outVbf, Wt11m, Wt12, Wt13, b12, b13,
                                        g3, be3, out_hE);
}

// Round 4
// 329.964 us; speedup vs baseline: 5.0199x; 1.2472x over previous
//
#include <hip/hip_runtime.h>
#include <hip/hip_bf16.h>
#include <math.h>

#define Hdim 128
#define Kn 48
#define NN 4096
#define FFH 512
#define LN_EPS 1e-5f

typedef __attribute__((ext_vector_type(8))) short bf16x8;
typedef __attribute__((ext_vector_type(4))) float floatx4;
typedef unsigned short ushort_t;

// chunk-major LDS tile: element (row,k) -> (k/8)*784 + row*16 + (k%8)*2
#define CMA(row, col) ((((col) >> 3) * 784) + ((row) << 4) + (((col)&7) << 1))

// tanh-approx GELU (|err vs erf-gelu| < ~3e-3)
__device__ __forceinline__ float gelu_f(float x) {
    float x2 = x * x;
    float u = x * fmaf(x2, -0.1029454f, -2.3022081f);
    return x * __builtin_amdgcn_rcpf(1.0f + exp2f(u));
}

__device__ __forceinline__ ushort_t f2bf(float f) {
    __hip_bfloat16 h = __float2bfloat16(f);
    return *reinterpret_cast<ushort_t*>(&h);
}
__device__ __forceinline__ float bf2f(ushort_t h) {
    union { unsigned u; float f; } v;
    v.u = ((unsigned)h) << 16;
    return v.f;
}

// ---------------------------------------------------------------------------
// convert_all: blocks 0..271   : weight transposes -> fragment-linear bf16
//              blocks 272..527 : hV fp32 -> bf16 (coalesced)
//              blocks 528..783 : pre_self GEMV (selfA = b1 + hV @ W1[0:128])
// fragment-linear: W'(n,k) at ((n>>4)*KD32 + (k>>5))*512 + ((k>>3)&3)*128
//                  + (n&15)*8 + (k&7)    (ushort units; KD32 = K/32)
// ---------------------------------------------------------------------------
__global__ __launch_bounds__(256) void convert_all(
    const float* __restrict__ W1, const float* __restrict__ W11,
    const float* __restrict__ W2, const float* __restrict__ W3,
    const float* __restrict__ W12, const float* __restrict__ W13,
    const float* __restrict__ W_in, const float* __restrict__ W_out,
    const float* __restrict__ hV, const float* __restrict__ b1,
    ushort_t* __restrict__ Wt1m, ushort_t* __restrict__ Wt11m,
    ushort_t* __restrict__ Wt11a, ushort_t* __restrict__ Wt2,
    ushort_t* __restrict__ Wt3, ushort_t* __restrict__ Wt12,
    ushort_t* __restrict__ Wt13, ushort_t* __restrict__ WtIn,
    ushort_t* __restrict__ WtOut, ushort_t* __restrict__ hVbf,
    float* __restrict__ selfA) {
    __shared__ __align__(16) char cmem[8448];
    const int b = blockIdx.x, t = threadIdx.x;

    if (b < 272) {
        // ---- tiled transpose+cast to fragment-linear layout ----
        const float* src;
        ushort_t* dst;
        int K, C, rowOff, tile;
        if (b < 32)       { src = W1;   dst = Wt1m;  K = 256; C = 128; rowOff = 128; tile = b; }
        else if (b < 64)  { src = W11;  dst = Wt11m; K = 256; C = 128; rowOff = 128; tile = b - 32; }
        else if (b < 80)  { src = W11;  dst = Wt11a; K = 128; C = 128; rowOff = 0;   tile = b - 64; }
        else if (b < 96)  { src = W2;   dst = Wt2;   K = 128; C = 128; rowOff = 0;   tile = b - 80; }
        else if (b < 112) { src = W3;   dst = Wt3;   K = 128; C = 128; rowOff = 0;   tile = b - 96; }
        else if (b < 128) { src = W12;  dst = Wt12;  K = 128; C = 128; rowOff = 0;   tile = b - 112; }
        else if (b < 144) { src = W13;  dst = Wt13;  K = 128; C = 128; rowOff = 0;   tile = b - 128; }
        else if (b < 208) { src = W_in; dst = WtIn;  K = 128; C = 512; rowOff = 0;   tile = b - 144; }
        else              { src = W_out;dst = WtOut; K = 512; C = 128; rowOff = 0;   tile = b - 208; }
        const int tpr = C >> 5;               // tiles per k-row
        const int tk = tile / tpr, tn = tile % tpr;
        const int tr0 = tk * 32, tc0 = tn * 32;
        const int KD32 = K >> 5;
        float (*s)[33] = (float(*)[33])cmem;
        // load 32x32 (coalesced)
#pragma unroll
        for (int i = 0; i < 4; ++i) {
            int r = (t >> 5) + i * 8, c = t & 31;
            s[r][c] = src[(size_t)(rowOff + tr0 + r) * C + tc0 + c];
        }
        __syncthreads();
        // write: 128 threads, 8 consecutive k each -> one uint4
        if (t < 128) {
            int n_loc = t >> 2, kc0 = (t & 3) * 8;
            int n = tc0 + n_loc, k = tr0 + kc0;
            ushort_t o[8];
#pragma unroll
            for (int e = 0; e < 8; ++e) o[e] = f2bf(s[kc0 + e][n_loc]);
            size_t idx = (size_t)((n >> 4) * KD32 + (k >> 5)) * 512 +
                         ((k >> 3) & 3) * 128 + (n & 15) * 8;
            *(uint4*)(dst + idx) = *(const uint4*)o;
        }
    } else if (b < 528) {
        // ---- hV -> bf16 ----
        int i = (b - 272) * 2048 + t * 8;
        float4 a = *(const float4*)(hV + (size_t)i);
        float4 c = *(const float4*)(hV + (size_t)i + 4);
        ushort_t o[8] = {f2bf(a.x), f2bf(a.y), f2bf(a.z), f2bf(a.w),
                         f2bf(c.x), f2bf(c.y), f2bf(c.z), f2bf(c.w)};
        *(uint4*)(hVbf + (size_t)i) = *(const uint4*)o;
    } else {
        // ---- pre_self: 16 nodes/block, two 128-thread groups ----
        float (*xs)[Hdim] = (float(*)[Hdim])cmem;
        const int grp = t >> 7, o = t & 127;
        const int nb0 = (b - 528) * 16;
#pragma unroll
        for (int n = 0; n < 8; ++n)
            xs[grp * 8 + n][o] = hV[(size_t)(nb0 + grp * 8 + n) * Hdim + o];
        __syncthreads();
        float acc[8];
        const float bo = b1[o];
#pragma unroll
        for (int n = 0; n < 8; ++n) acc[n] = bo;
        for (int i = 0; i < Hdim; i += 4) {
            const float w0 = W1[(i + 0) * Hdim + o];
            const float w1 = W1[(i + 1) * Hdim + o];
            const float w2 = W1[(i + 2) * Hdim + o];
            const float w3 = W1[(i + 3) * Hdim + o];
#pragma unroll
            for (int n = 0; n < 8; ++n) {
                const float4 v = *(const float4*)&xs[grp * 8 + n][i];
                acc[n] = fmaf(v.x, w0, acc[n]);
                acc[n] = fmaf(v.y, w1, acc[n]);
                acc[n] = fmaf(v.z, w2, acc[n]);
                acc[n] = fmaf(v.w, w3, acc[n]);
            }
        }
#pragma unroll
        for (int n = 0; n < 8; ++n)
            selfA[(size_t)(nb0 + grp * 8 + n) * Hdim + o] = acc[n];
    }
}

// ---------------------------------------------------------------------------
// edge_mlp<MODE>: 1 node/block, 256 threads (4 waves; wave w owns cols w*32..).
// LDS tiles chunk-major (imm-offset ds_read_b128, conflict-free).
// T0: 48x256 [hE | gathered hV_nbr]; T1: 48x128; T2 aliases T0 chunks 16..31.
// Weights: fragment-linear in ws, coalesced 16B/lane global loads (L2-hot).
// MODE 0: masked col-sum /30, +hV, LN1 -> hV2.  MODE 1: +hE, row-LN3 -> out_hE
// ---------------------------------------------------------------------------
template <int MODE>
__global__ __launch_bounds__(256, 4) void edge_mlp(
    const float* __restrict__ hV, const float* __restrict__ hE,
    const int* __restrict__ Eidx, const float* __restrict__ maskAtt,
    const float* __restrict__ selfA, const ushort_t* __restrict__ hVbf,
    const ushort_t* __restrict__ WtA, const ushort_t* __restrict__ WtB,
    const ushort_t* __restrict__ WtC, const float* __restrict__ bias2,
    const float* __restrict__ bias3, const float* __restrict__ gamma,
    const float* __restrict__ beta, float* __restrict__ outp) {
    __shared__ __align__(16) char T0[32 * 784];   // 25088
    __shared__ __align__(16) char T1[16 * 784];   // 12544
    __shared__ int idx_s[Kn];
    __shared__ float dh_s[128];
    __shared__ float rsum[Kn][4], rsum2[Kn][4];
    __shared__ float mu_s[Kn], rs_s[Kn];
    __shared__ float rw[8];
    char* T2 = T0 + 16 * 784;                     // aliases neighbor half

    const int tid = threadIdx.x;
    const int lane = tid & 63;
    const int w = tid >> 6;
    const int l15 = lane & 15, l4 = lane >> 4;
    const int n = blockIdx.x;
    const int n0 = w * 32;
    const int bbase = (n >> 11) << 11;
    const int abase = l4 * 784 + l15 * 16;        // A-frag per-thread base
    const int fbase = l4 * 128 + l15 * 8;         // B-frag per-lane offset

    if (tid < Kn) idx_s[tid] = Eidx[(size_t)n * Kn + tid];
    // stage hE (fp32 -> bf16, chunk-major)
    {
        const float4* src = (const float4*)(hE + (size_t)n * Kn * Hdim);
#pragma unroll
        for (int it = 0; it < 6; ++it) {
            int i = tid + it * 256;
            float4 v = src[i];
            int row = i >> 5, j = i & 31;
            unsigned lo = f2bf(v.x) | ((unsigned)f2bf(v.y) << 16);
            unsigned hi = f2bf(v.z) | ((unsigned)f2bf(v.w) << 16);
            *(uint2*)(T0 + (j >> 1) * 784 + row * 16 + (j & 1) * 8) =
                make_uint2(lo, hi);
        }
    }
    __syncthreads();
    // gather neighbor bf16 rows into chunks 16..31 (16B/lane, coalesced)
#pragma unroll
    for (int it = 0; it < 3; ++it) {
        int i = tid + it * 256;
        int row = i >> 4, c = i & 15;
        uint4 v =
            *(const uint4*)(hVbf + (size_t)(bbase + idx_s[row]) * Hdim + c * 8);
        *(uint4*)(T0 + (16 + c) * 784 + row * 16) = v;
    }
    __syncthreads();

    floatx4 acc[3][2];
#pragma unroll
    for (int mt = 0; mt < 3; ++mt)
#pragma unroll
        for (int nt = 0; nt < 2; ++nt) acc[mt][nt] = (floatx4)0.0f;

    // ---- layer 1: K=256 ----
#pragma unroll
    for (int kk = 0; kk < 8; ++kk) {
        bf16x8 a[3], bb[2];
#pragma unroll
        for (int mt = 0; mt < 3; ++mt)
            a[mt] = *(const bf16x8*)(T0 + abase + mt * 256 + kk * 3136);
#pragma unroll
        for (int nt = 0; nt < 2; ++nt)
            bb[nt] = *(const bf16x8*)(WtA + ((w * 2 + nt) * 8 + kk) * 512 +
                                      fbase);
#pragma unroll
        for (int mt = 0; mt < 3; ++mt)
#pragma unroll
            for (int nt = 0; nt < 2; ++nt)
                acc[mt][nt] = __builtin_amdgcn_mfma_f32_16x16x32_bf16(
                    a[mt], bb[nt], acc[mt][nt], 0, 0, 0);
    }
    // layer-1 epilogue: + selfA broadcast, GELU -> T1
    {
        float sA[2];
#pragma unroll
        for (int nt = 0; nt < 2; ++nt)
            sA[nt] = selfA[(size_t)n * Hdim + n0 + nt * 16 + l15];
#pragma unroll
        for (int mt = 0; mt < 3; ++mt)
#pragma unroll
            for (int nt = 0; nt < 2; ++nt) {
                const int col = n0 + nt * 16 + l15;
#pragma unroll
                for (int r = 0; r < 4; ++r) {
                    float v = gelu_f(acc[mt][nt][r] + sA[nt]);
                    int row = mt * 16 + l4 * 4 + r;
                    *(ushort_t*)(T1 + CMA(row, col)) = f2bf(v);
                }
            }
    }
    __syncthreads();

    // ---- layer 2: K=128 ----
    {
        float bv[2];
#pragma unroll
        for (int nt = 0; nt < 2; ++nt) bv[nt] = bias2[n0 + nt * 16 + l15];
#pragma unroll
        for (int mt = 0; mt < 3; ++mt)
#pragma unroll
            for (int nt = 0; nt < 2; ++nt)
                acc[mt][nt] = (floatx4){bv[nt], bv[nt], bv[nt], bv[nt]};
    }
#pragma unroll
    for (int kk = 0; kk < 4; ++kk) {
        bf16x8 a[3], bb[2];
#pragma unroll
        for (int mt = 0; mt < 3; ++mt)
            a[mt] = *(const bf16x8*)(T1 + abase + mt * 256 + kk * 3136);
#pragma unroll
        for (int nt = 0; nt < 2; ++nt)
            bb[nt] = *(const bf16x8*)(WtB + ((w * 2 + nt) * 4 + kk) * 512 +
                                      fbase);
#pragma unroll
        for (int mt = 0; mt < 3; ++mt)
#pragma unroll
            for (int nt = 0; nt < 2; ++nt)
                acc[mt][nt] = __builtin_amdgcn_mfma_f32_16x16x32_bf16(
                    a[mt], bb[nt], acc[mt][nt], 0, 0, 0);
    }
    __syncthreads();
#pragma unroll
    for (int mt = 0; mt < 3; ++mt)
#pragma unroll
        for (int nt = 0; nt < 2; ++nt) {
            const int col = n0 + nt * 16 + l15;
#pragma unroll
            for (int r = 0; r < 4; ++r) {
                float v = gelu_f(acc[mt][nt][r]);
                int row = mt * 16 + l4 * 4 + r;
                *(ushort_t*)(T2 + CMA(row, col)) = f2bf(v);
            }
        }
    __syncthreads();

    // ---- layer 3: K=128, no activation ----
    {
        float bv[2];
#pragma unroll
        for (int nt = 0; nt < 2; ++nt) bv[nt] = bias3[n0 + nt * 16 + l15];
#pragma unroll
        for (int mt = 0; mt < 3; ++mt)
#pragma unroll
            for (int nt = 0; nt < 2; ++nt)
                acc[mt][nt] = (floatx4){bv[nt], bv[nt], bv[nt], bv[nt]};
    }
#pragma unroll
    for (int kk = 0; kk < 4; ++kk) {
        bf16x8 a[3], bb[2];
#pragma unroll
        for (int mt = 0; mt < 3; ++mt)
            a[mt] = *(const bf16x8*)(T2 + abase + mt * 256 + kk * 3136);
#pragma unroll
        for (int nt = 0; nt < 2; ++nt)
            bb[nt] = *(const bf16x8*)(WtC + ((w * 2 + nt) * 4 + kk) * 512 +
                                      fbase);
#pragma unroll
        for (int mt = 0; mt < 3; ++mt)
#pragma unroll
            for (int nt = 0; nt < 2; ++nt)
                acc[mt][nt] = __builtin_amdgcn_mfma_f32_16x16x32_bf16(
                    a[mt], bb[nt], acc[mt][nt], 0, 0, 0);
    }

    if (MODE == 0) {
        // masked column-sum over 48 edges, /30, +hV, LN1
        float mav[3][4];
#pragma unroll
        for (int mt = 0; mt < 3; ++mt)
#pragma unroll
            for (int r = 0; r < 4; ++r)
                mav[mt][r] = maskAtt[(size_t)n * Kn + mt * 16 + l4 * 4 + r];
#pragma unroll
        for (int nt = 0; nt < 2; ++nt) {
            float c = 0.0f;
#pragma unroll
            for (int mt = 0; mt < 3; ++mt)
#pragma unroll
                for (int r = 0; r < 4; ++r)
                    c = fmaf(mav[mt][r], acc[mt][nt][r], c);
            c += __shfl_xor(c, 16);
            c += __shfl_xor(c, 32);
            if (l4 == 0) dh_s[n0 + nt * 16 + l15] = c;
        }
        __syncthreads();
        float x = 0.0f;
        if (tid < 128) {
            x = hV[(size_t)n * Hdim + tid] + dh_s[tid] * (1.0f / 30.0f);
            float s = x, s2 = x * x;
#pragma unroll
            for (int off = 32; off > 0; off >>= 1) {
                s += __shfl_xor(s, off);
                s2 += __shfl_xor(s2, off);
            }
            if (lane == 0) {
                rw[w * 2] = s;
                rw[w * 2 + 1] = s2;
            }
        }
        __syncthreads();
        if (tid < 128) {
            const float ts = rw[0] + rw[2], ts2 = rw[1] + rw[3];
            const float mu = ts * (1.0f / Hdim);
            const float var = ts2 * (1.0f / Hdim) - mu * mu;
            const float rs = rsqrtf(var + LN_EPS);
            outp[(size_t)n * Hdim + tid] =
                gamma[tid] * (x - mu) * rs + beta[tid];
        }
    } else {
        // residual (bf16 hE from T0 chunks 0..15) + per-row LN3 -> out_hE
        float xv[3][2][4];
#pragma unroll
        for (int mt = 0; mt < 3; ++mt)
#pragma unroll
            for (int nt = 0; nt < 2; ++nt) {
                const int col = n0 + nt * 16 + l15;
#pragma unroll
                for (int r = 0; r < 4; ++r) {
                    int row = mt * 16 + l4 * 4 + r;
                    ushort_t hv = *(const ushort_t*)(T0 + CMA(row, col));
                    xv[mt][nt][r] = acc[mt][nt][r] + bf2f(hv);
                }
            }
#pragma unroll
        for (int mt = 0; mt < 3; ++mt)
#pragma unroll
            for (int r = 0; r < 4; ++r) {
                float s = xv[mt][0][r] + xv[mt][1][r];
                float s2 = xv[mt][0][r] * xv[mt][0][r] +
                           xv[mt][1][r] * xv[mt][1][r];
#pragma unroll
                for (int off = 1; off < 16; off <<= 1) {
                    s += __shfl_xor(s, off);
                    s2 += __shfl_xor(s2, off);
                }
                if (l15 == 0) {
                    int row = mt * 16 + l4 * 4 + r;
                    rsum[row][w] = s;
                    rsum2[row][w] = s2;
                }
            }
        __syncthreads();
        if (tid < Kn) {
            float s = rsum[tid][0] + rsum[tid][1] + rsum[tid][2] + rsum[tid][3];
            float s2 =
                rsum2[tid][0] + rsum2[tid][1] + rsum2[tid][2] + rsum2[tid][3];
            float mu = s * (1.0f / Hdim);
            float var = s2 * (1.0f / Hdim) - mu * mu;
            mu_s[tid] = mu;
            rs_s[tid] = rsqrtf(var + LN_EPS);
        }
        __syncthreads();
        float gv[2], bv[2];
#pragma unroll
        for (int nt = 0; nt < 2; ++nt) {
            gv[nt] = gamma[n0 + nt * 16 + l15];
            bv[nt] = beta[n0 + nt * 16 + l15];
        }
#pragma unroll
        for (int mt = 0; mt < 3; ++mt)
#pragma unroll
            for (int nt = 0; nt < 2; ++nt) {
                const int col = n0 + nt * 16 + l15;
#pragma unroll
                for (int r = 0; r < 4; ++r) {
                    int row = mt * 16 + l4 * 4 + r;
                    float y = gv[nt] * (xv[mt][nt][r] - mu_s[row]) *
                                  rs_s[row] + bv[nt];
                    outp[((size_t)n * Kn + row) * Hdim + col] = y;
                }
            }
    }
}

// ---------------------------------------------------------------------------
// ffn_mfma: 16 nodes/block, 512 threads (8 waves), 256 blocks.
// y = LN2(x + gelu(x@W_in+b_in)@W_out+b_out)*maskV  -> out fp32 + bf16 copy
// fused: selfA2 = b11 + y_bf16 @ W11[0:128]  (edge-update self term)
// ---------------------------------------------------------------------------
__global__ __launch_bounds__(512) void ffn_mfma(
    const float* __restrict__ hV2, const ushort_t* __restrict__ WtIn,
    const float* __restrict__ b_in, const ushort_t* __restrict__ WtOut,
    const float* __restrict__ b_out, const ushort_t* __restrict__ Wt11a,
    const float* __restrict__ b11, const float* __restrict__ g2,
    const float* __restrict__ be2, const float* __restrict__ maskV,
    float* __restrict__ outp, ushort_t* __restrict__ outb,
    float* __restrict__ selfA2) {
    __shared__ __align__(16) char XF[16 * 272];   // 16x128 bf16 chunk-major
    __shared__ __align__(16) char HF[64 * 272];   // 16x512 bf16 chunk-major
    __shared__ float rsF[16][8], rs2F[16][8], muF[16], rstdF[16];

    const int tid = threadIdx.x;
    const int lane = tid & 63;
    const int w = tid >> 6;
    const int l15 = lane & 15, l4 = lane >> 4;
    const int rg0 = blockIdx.x * 16;
    const int abase = l4 * 272 + l15 * 16;
    const int fbase = l4 * 128 + l15 * 8;

    {
        const float4* src = (const float4*)(hV2 + (size_t)rg0 * Hdim);
        int i = tid;  // 512 float4
        float4 v = src[i];
        int row = i >> 5, j = i & 31;
        unsigned lo = f2bf(v.x) | ((unsigned)f2bf(v.y) << 16);
        unsigned hi = f2bf(v.z) | ((unsigned)f2bf(v.w) << 16);
        *(uint2*)(XF + (j >> 1) * 272 + row * 16 + (j & 1) * 8) =
            make_uint2(lo, hi);
    }
    __syncthreads();
    // L1: wave w -> col-tiles w*4..w*4+3 (N=512), K=128
    {
        floatx4 a1[4];
#pragma unroll
        for (int j = 0; j < 4; ++j) {
            float bv = b_in[(w * 4 + j) * 16 + l15];
            a1[j] = (floatx4){bv, bv, bv, bv};
        }
#pragma unroll
        for (int kk = 0; kk < 4; ++kk) {
            bf16x8 af = *(const bf16x8*)(XF + abase + kk * 1088);
#pragma unroll
            for (int j = 0; j < 4; ++j) {
                bf16x8 bf = *(const bf16x8*)(WtIn +
                             ((w * 4 + j) * 4 + kk) * 512 + fbase);
                a1[j] = __builtin_amdgcn_mfma_f32_16x16x32_bf16(af, bf, a1[j],
                                                                0, 0, 0);
            }
        }
#pragma unroll
        for (int j = 0; j < 4; ++j) {
            const int col = (w * 4 + j) * 16 + l15;
#pragma unroll
            for (int r = 0; r < 4; ++r) {
                int row = l4 * 4 + r;
                *(ushort_t*)(HF + ((col >> 3) * 272) + row * 16 +
                             ((col & 7) << 1)) = f2bf(gelu_f(a1[j][r]));
            }
        }
    }
    __syncthreads();
    // L2: wave w -> col-tile w (N=128), K=512
    floatx4 o2;
    {
        float bv = b_out[w * 16 + l15];
        o2 = (floatx4){bv, bv, bv, bv};
    }
#pragma unroll
    for (int kk = 0; kk < 16; ++kk) {
        bf16x8 af = *(const bf16x8*)(HF + abase + kk * 1088);
        bf16x8 bf = *(const bf16x8*)(WtOut + (w * 16 + kk) * 512 + fbase);
        o2 = __builtin_amdgcn_mfma_f32_16x16x32_bf16(af, bf, o2, 0, 0, 0);
    }
    // epilogue: residual + LN2 + mask
    const int colw = w * 16 + l15;
    float xv[4];
#pragma unroll
    for (int r = 0; r < 4; ++r)
        xv[r] = hV2[(size_t)(rg0 + l4 * 4 + r) * Hdim + colw] + o2[r];
#pragma unroll
    for (int r = 0; r < 4; ++r) {
        float s = xv[r], s2 = xv[r] * xv[r];
#pragma unroll
        for (int off = 1; off < 16; off <<= 1) {
            s += __shfl_xor(s, off);
            s2 += __shfl_xor(s2, off);
        }
        if (l15 == 0) {
            rsF[l4 * 4 + r][w] = s;
            rs2F[l4 * 4 + r][w] = s2;
        }
    }
    __syncthreads();
    if (tid < 16) {
        float s = 0.0f, s2 = 0.0f;
#pragma unroll
        for (int q = 0; q < 8; ++q) { s += rsF[tid][q]; s2 += rs2F[tid][q]; }
        float mu = s * (1.0f / Hdim);
        float var = s2 * (1.0f / Hdim) - mu * mu;
        muF[tid] = mu;
        rstdF[tid] = rsqrtf(var + LN_EPS);
    }
    __syncthreads();
    {
        float gvv = g2[colw], bvv = be2[colw];
#pragma unroll
        for (int r = 0; r < 4; ++r) {
            int row = l4 * 4 + r;
            float y = (gvv * (xv[r] - muF[row]) * rstdF[row] + bvv) *
                      maskV[rg0 + row];
            ushort_t yb = f2bf(y);
            outp[(size_t)(rg0 + row) * Hdim + colw] = y;
            outb[(size_t)(rg0 + row) * Hdim + colw] = yb;
            *(ushort_t*)(XF + ((colw >> 3) * 272) + row * 16 +
                         ((colw & 7) << 1)) = yb;
        }
    }
    __syncthreads();
    // fused selfA2 GEMM: wave w -> col-tile w (N=128), K=128
    {
        float bv = b11[colw];
        floatx4 sa = (floatx4){bv, bv, bv, bv};
#pragma unroll
        for (int kk = 0; kk < 4; ++kk) {
            bf16x8 af = *(const bf16x8*)(XF + abase + kk * 1088);
            bf16x8 bf = *(const bf16x8*)(Wt11a + (w * 4 + kk) * 512 + fbase);
            sa = __builtin_amdgcn_mfma_f32_16x16x32_bf16(af, bf, sa, 0, 0, 0);
        }
#pragma unroll
        for (int r = 0; r < 4; ++r)
            selfA2[(size_t)(rg0 + l4 * 4 + r) * Hdim + colw] = sa[r];
    }
}

// ---------------------------------------------------------------------------
extern "C" void kernel_launch(void* const* d_in, const int* in_sizes, int n_in,
                              void* d_out, int out_size, void* d_ws,
                              size_t ws_size, hipStream_t stream) {
    const float* hV = (const float*)d_in[0];
    const float* hE = (const float*)d_in[1];
    const int* Eidx = (const int*)d_in[2];
    const float* maskV = (const float*)d_in[3];
    const float* maskAtt = (const float*)d_in[4];
    const float* W1 = (const float*)d_in[5];
    const float* b1 = (const float*)d_in[6];
    const float* W2 = (const float*)d_in[7];
    const float* b2 = (const float*)d_in[8];
    const float* W3 = (const float*)d_in[9];
    const float* b3 = (const float*)d_in[10];
    const float* W11 = (const float*)d_in[11];
    const float* b11 = (const float*)d_in[12];
    const float* W12 = (const float*)d_in[13];
    const float* b12 = (const float*)d_in[14];
    const float* W13 = (const float*)d_in[15];
    const float* b13 = (const float*)d_in[16];
    const float* g1 = (const float*)d_in[17];
    const float* be1 = (const float*)d_in[18];
    const float* g2 = (const float*)d_in[19];
    const float* be2 = (const float*)d_in[20];
    const float* g3 = (const float*)d_in[21];
    const float* be3 = (const float*)d_in[22];
    const float* W_in = (const float*)d_in[23];
    const float* b_in = (const float*)d_in[24];
    const float* W_out = (const float*)d_in[25];
    const float* b_out = (const float*)d_in[26];

    float* out_hV = (float*)d_out;
    float* out_hE = out_hV + (size_t)NN * Hdim;
    float* ws = (float*)d_ws;
    float* hV2 = ws;                       // 524288 f32
    float* selfA = ws + 524288;            // 524288 f32
    ushort_t* u = (ushort_t*)(ws + 1048576);
    ushort_t* hVbf = u;                    // 524288
    ushort_t* outVbf = u + 524288;         // 524288
    ushort_t* Wt1m = u + 1048576;          // 32768
    ushort_t* Wt11m = u + 1081344;         // 32768
    ushort_t* Wt11a = u + 1114112;         // 16384
    ushort_t* Wt2 = u + 1130496;           // 16384
    ushort_t* Wt3 = u + 1146880;           // 16384
    ushort_t* Wt12 = u + 1163264;          // 16384
    ushort_t* Wt13 = u + 1179648;          // 16384
    ushort_t* WtIn = u + 1196032;          // 65536
    ushort_t* WtOut = u + 1261568;         // 65536

    convert_all<<<784, 256, 0, stream>>>(W1, W11, W2, W3, W12, W13, W_in,
                                         W_out, hV, b1, Wt1m, Wt11m, Wt11a,
                                         Wt2, Wt3, Wt12, Wt13, WtIn, WtOut,
                                         hVbf, selfA);
    // phase 1: node message + LN1 -> hV2
    edge_mlp<0><<<NN, 256, 0, stream>>>(hV, hE, Eidx, maskAtt, selfA, hVbf,
                                        Wt1m, Wt2, Wt3, b2, b3, g1, be1, hV2);
    // phase 2: FFN + LN2 + mask -> out_hV (+ bf16 copy) + fused selfA2
    ffn_mfma<<<NN / 16, 512, 0, stream>>>(hV2, WtIn, b_in, WtOut, b_out,
                                          Wt11a, b11, g2, be2, maskV, out_hV,
                                          outVbf, selfA);
    // phase 3: edge update + LN3 -> out_hE
    edge_mlp<1><<<NN, 256, 0, stream>>>(nullptr, hE, Eidx, nullptr, selfA,
                                        outVbf, Wt11m, Wt12, Wt13, b12, b13,
                                        g3, be3, out_hE);
}